// Round 1
// 1248.773 us; speedup vs baseline: 1.0460x; 1.0460x over previous
//
#include <hip/hip_runtime.h>
#include <cstdint>
#include <cstddef>

typedef _Float16 f16;
typedef _Float16 f16x8 __attribute__((ext_vector_type(8)));
typedef _Float16 f16x4 __attribute__((ext_vector_type(4)));
typedef float    f32x4 __attribute__((ext_vector_type(4)));

constexpr int S_ = 512, D_ = 2048, H_ = 32, HD_ = 64, I_ = 8192;
constexpr int M_ = 4096;   // B*S
constexpr int IH_ = 4096;  // I/2 (FFN processed in two halves)

enum { OP_F32 = 0, OP_QKT = 3, OP_PV = 4, OP_QKV = 6, OP_GU = 9, OP_ADD = 10 };

__device__ __forceinline__ void gl_lds16(const void* g, void* lds) {
  __builtin_amdgcn_global_load_lds(
      (const __attribute__((address_space(1))) void*)g,
      (__attribute__((address_space(3))) void*)lds, 16, 0, 0);
}

// C = A @ B^T. A f16 MxK row-major, B f16 NxK row-major; both staged via
// global_load_lds (16B/lane, wave-uniform LDS base -> linear layout).
// OP_GU: second B (B2) staged into upper half of Bs; epilogue silu(g)*u.
template <int BM, int BN, int WR, int WC, int OP>
__global__ __launch_bounds__(256, 2) void gemm_k(
    const f16* __restrict__ A, int lda,
    const f16* __restrict__ B, int ldb,
    void* __restrict__ Cp, int ldc,
    int K, int bh0, const float* __restrict__ relmean,
    const f16* __restrict__ B2) {
  constexpr int BK = 32;
  constexpr bool GU = (OP == OP_GU);
  constexpr int WM = BM / WR, WN = BN / WC;
  constexpr int IM = WM / 16, IN = WN / 16;
  constexpr int CA = BM / 64, CB = BN / 64;
  __shared__ __align__(16) f16 As[BM * BK];
  __shared__ __align__(16) f16 Bs[(GU ? 2 : 1) * BN * BK];
  const int tid = threadIdx.x, wave = tid >> 6, lane = tid & 63;
  const int wm = wave / WC, wn = wave % WC;
  const int bn = blockIdx.x, bm = blockIdx.y, bz = blockIdx.z;

  long aoff = 0, boff = 0;
  if constexpr (OP == OP_QKT) {
    int bh = bh0 + bz;
    long hb = (long)(bh >> 5) * (S_ * D_) + (long)(bh & (H_ - 1)) * HD_;
    aoff = hb; boff = hb;
  }
  if constexpr (OP == OP_PV) {
    int bh = bh0 + bz;
    aoff = (long)bz * S_ * S_;       // attn probs, chunk-local
    boff = (long)bh * HD_ * S_;      // vT global
  }
  if constexpr (OP == OP_QKV) boff = (long)bz * D_ * D_;  // wqT/wkT/wvT contiguous

  const f16* Ab = A + aoff + (long)bm * BM * lda;
  const f16* Bb = B + boff + (long)bn * BN * ldb;
  const f16* Bb2 = nullptr;
  if constexpr (GU) Bb2 = B2 + (long)bn * BN * ldb;

  f32x4 acc[IM][IN], acc2[IM][IN];
#pragma unroll
  for (int i = 0; i < IM; i++)
#pragma unroll
    for (int j = 0; j < IN; j++) {
      acc[i][j] = {0.f, 0.f, 0.f, 0.f};
      if constexpr (GU) acc2[i][j] = {0.f, 0.f, 0.f, 0.f};
    }

  const int lr = lane >> 2, l4 = lane & 3;   // NT staging: 4x16B per 16-row region
  const int q8 = (lane >> 4) * 8, l15 = lane & 15;

  for (int kt = 0; kt < K; kt += BK) {
#pragma unroll
    for (int c = 0; c < CA; c++) {
      int reg = wave * CA + c;               // wave-uniform region id
      gl_lds16(Ab + (long)(reg * 16 + lr) * lda + kt + l4 * 8, &As[reg * 512]);
    }
#pragma unroll
    for (int c = 0; c < CB; c++) {
      int reg = wave * CB + c;
      gl_lds16(Bb + (long)(reg * 16 + lr) * ldb + kt + l4 * 8, &Bs[reg * 512]);
      if constexpr (GU)
        gl_lds16(Bb2 + (long)(reg * 16 + lr) * ldb + kt + l4 * 8,
                 &Bs[BN * BK + reg * 512]);
    }
    __syncthreads();
    f16x8 af[IM], bf[IN], bf2[IN];
#pragma unroll
    for (int i = 0; i < IM; i++)
      af[i] = *(const f16x8*)&As[(wm * WM + i * 16 + l15) * BK + q8];
#pragma unroll
    for (int j = 0; j < IN; j++) {
      int colL = wn * WN + j * 16 + l15;
      bf[j] = *(const f16x8*)&Bs[colL * BK + q8];
      if constexpr (GU) bf2[j] = *(const f16x8*)&Bs[BN * BK + colL * BK + q8];
    }
#pragma unroll
    for (int i = 0; i < IM; i++)
#pragma unroll
      for (int j = 0; j < IN; j++) {
        acc[i][j] = __builtin_amdgcn_mfma_f32_16x16x32_f16(af[i], bf[j], acc[i][j], 0, 0, 0);
        if constexpr (GU)
          acc2[i][j] = __builtin_amdgcn_mfma_f32_16x16x32_f16(af[i], bf2[j], acc2[i][j], 0, 0, 0);
      }
    __syncthreads();
  }

  // Epilogue. C/D layout: col = lane&15, row = (lane>>4)*4 + reg  [m89/m91]
  const int r0 = bm * BM + wm * WM + (lane >> 4) * 4;
  const int c0 = bn * BN + wn * WN + l15;
#pragma unroll
  for (int i = 0; i < IM; i++) {
#pragma unroll
    for (int j = 0; j < IN; j++) {
      int rowb = r0 + i * 16;
      int col = c0 + j * 16;
      if constexpr (OP == OP_F32) {
        float* C = (float*)Cp;
#pragma unroll
        for (int t = 0; t < 4; t++) C[(long)(rowb + t) * ldc + col] = acc[i][j][t];
      } else if constexpr (OP == OP_ADD) {
        float* C = (float*)Cp;
#pragma unroll
        for (int t = 0; t < 4; t++) C[(long)(rowb + t) * ldc + col] += acc[i][j][t];
      } else if constexpr (OP == OP_GU) {
        f16* C = (f16*)Cp;
#pragma unroll
        for (int t = 0; t < 4; t++) {
          float g = acc[i][j][t], u = acc2[i][j][t];
          C[(long)(rowb + t) * ldc + col] = (f16)(g / (1.f + __expf(-g)) * u);
        }
      } else if constexpr (OP == OP_QKT) {
        f16* C = (f16*)Cp + (long)bz * S_ * S_;
#pragma unroll
        for (int t = 0; t < 4; t++) {
          int r = rowb + t;
          C[(long)r * S_ + col] = (f16)(acc[i][j][t] * 0.125f + relmean[col - r + 511]);
        }
      } else if constexpr (OP == OP_PV) {
        int bh = bh0 + bz;
        f16* C = (f16*)Cp + (long)(bh >> 5) * (S_ * D_) + (long)(bh & (H_ - 1)) * HD_;
#pragma unroll
        for (int t = 0; t < 4; t++) C[(long)(rowb + t) * ldc + col] = (f16)acc[i][j][t];
      } else if constexpr (OP == OP_QKV) {
        f16* C = (f16*)Cp;
        if (bz < 2) {  // q or k: plain f16 rows
          f16* Cq = C + (long)bz * M_ * D_;
#pragma unroll
          for (int t = 0; t < 4; t++) Cq[(long)(rowb + t) * ldc + col] = (f16)acc[i][j][t];
        } else {       // v: write transposed vT[(b*H+h)*HD+hd][s]
          f16* Cv = C + (long)2 * M_ * D_;
          int b = rowb >> 9, s0 = rowb & 511, h = col >> 6, hd = col & 63;
          f16x4 pk;
#pragma unroll
          for (int t = 0; t < 4; t++) pk[t] = (f16)acc[i][j][t];
          *(f16x4*)&Cv[((long)(b * H_ + h) * HD_ + hd) * S_ + s0] = pk;
        }
      }
    }
  }
}

// fp32 [K][N] column-slice/row-slice -> f16 [Nh][Krows] (N x K, "NT" weight).
// out[n][k] = (f16) in[(k0+k)*ldin + n0+n].  64x64 tiles via LDS.
__global__ __launch_bounds__(256) void transpose_k(
    const float* __restrict__ in, int ldin, int k0, int n0,
    f16* __restrict__ out, int ldout) {
  __shared__ f16 t[64][68];  // stride 68: f16x4-aligned, conflict-lite
  const int kb = blockIdx.x * 64, nb = blockIdx.y * 64;
  const int tid = threadIdx.x;
  {
    const int kr = tid >> 4, nc = (tid & 15) * 4;
    const float* src = in + (long)(k0 + kb) * ldin + (n0 + nb);
#pragma unroll
    for (int i = 0; i < 4; i++) {
      int k = kr + i * 16;
      f32x4 v = *(const f32x4*)&src[(long)k * ldin + nc];
#pragma unroll
      for (int j = 0; j < 4; j++) t[nc + j][k] = (f16)v[j];
    }
  }
  __syncthreads();
  {
    const int n = tid >> 2, kc = (tid & 3) * 16;
    f16* dst = out + (long)(nb + n) * ldout + (kb + kc);
#pragma unroll
    for (int j = 0; j < 4; j++)
      *(f16x4*)&dst[j * 4] = *(const f16x4*)&t[n][kc + j * 4];
  }
}

__global__ void cvt_f16_k(const float* __restrict__ in, f16* __restrict__ out, int n4) {
  int i = blockIdx.x * 256 + threadIdx.x;
  if (i >= n4) return;
  f32x4 v = ((const f32x4*)in)[i];
  f16x4 o;
#pragma unroll
  for (int t = 0; t < 4; t++) o[t] = (f16)v[t];
  ((f16x4*)out)[i] = o;
}

__global__ void relmean_k(const float* __restrict__ rel, float* __restrict__ rm) {
  int i = blockIdx.x * 256 + threadIdx.x;
  if (i >= 1023) return;
  float s = 0.f;
#pragma unroll 8
  for (int d = 0; d < 64; d++) s += rel[i * 64 + d];
  rm[i] = s * (1.f / 64.f);
}

// in-place row softmax over S_=512 f16, one wave per row, f16x8 vector I/O
__global__ __launch_bounds__(256) void softmax_k(f16* __restrict__ Sc) {
  int r = blockIdx.x * 4 + (threadIdx.x >> 6);
  int lane = threadIdx.x & 63;
  f16* s = Sc + (long)r * S_;
  f16x8 d = *(const f16x8*)&s[lane * 8];
  float v[8], mx = -1e30f;
#pragma unroll
  for (int i = 0; i < 8; i++) { v[i] = (float)d[i]; mx = fmaxf(mx, v[i]); }
  for (int off = 32; off; off >>= 1) mx = fmaxf(mx, __shfl_xor(mx, off));
  float sum = 0.f;
#pragma unroll
  for (int i = 0; i < 8; i++) { v[i] = __expf(v[i] - mx); sum += v[i]; }
  for (int off = 32; off; off >>= 1) sum += __shfl_xor(sum, off);
  float rs = 1.f / sum;
  f16x8 o;
#pragma unroll
  for (int i = 0; i < 8; i++) o[i] = (f16)(v[i] * rs);
  *(f16x8*)&s[lane * 8] = o;
}

// h1h = (f16) LN(X + Y) * g + b   (fp32 inputs, f16 out only)
__global__ __launch_bounds__(256) void ln1_k(const float* __restrict__ X,
                                             const float* __restrict__ Y,
                                             const float* __restrict__ g,
                                             const float* __restrict__ b,
                                             f16* __restrict__ outH) {
  int row = blockIdx.x;
  const float* x = X + (long)row * D_;
  const float* y = Y + (long)row * D_;
  int t = threadIdx.x;
  float v[8], sum = 0.f, sq = 0.f;
#pragma unroll
  for (int i = 0; i < 8; i++) {
    int idx = t + i * 256;
    float val = x[idx] + y[idx];
    v[i] = val; sum += val; sq += val * val;
  }
  for (int off = 32; off; off >>= 1) { sum += __shfl_down(sum, off); sq += __shfl_down(sq, off); }
  __shared__ float s1[4], s2[4];
  if ((t & 63) == 0) { s1[t >> 6] = sum; s2[t >> 6] = sq; }
  __syncthreads();
  sum = s1[0] + s1[1] + s1[2] + s1[3];
  sq = s2[0] + s2[1] + s2[2] + s2[3];
  float mu = sum * (1.f / D_);
  float rstd = rsqrtf(sq * (1.f / D_) - mu * mu + 1e-6f);
#pragma unroll
  for (int i = 0; i < 8; i++) {
    int idx = t + i * 256;
    outH[(long)row * D_ + idx] = (f16)((v[i] - mu) * rstd * g[idx] + b[idx]);
  }
}

// out = LN(X + Y) * g + b ; X = ffn accum (fp32), Y = h1h (f16 residual)
__global__ __launch_bounds__(256) void ln2f_k(const float* __restrict__ X,
                                              const f16* __restrict__ Y,
                                              const float* __restrict__ g,
                                              const float* __restrict__ b,
                                              float* __restrict__ outF) {
  int row = blockIdx.x;
  const float* x = X + (long)row * D_;
  const f16* y = Y + (long)row * D_;
  int t = threadIdx.x;
  float v[8], sum = 0.f, sq = 0.f;
#pragma unroll
  for (int i = 0; i < 8; i++) {
    int idx = t + i * 256;
    float val = x[idx] + (float)y[idx];
    v[i] = val; sum += val; sq += val * val;
  }
  for (int off = 32; off; off >>= 1) { sum += __shfl_down(sum, off); sq += __shfl_down(sq, off); }
  __shared__ float s1[4], s2[4];
  if ((t & 63) == 0) { s1[t >> 6] = sum; s2[t >> 6] = sq; }
  __syncthreads();
  sum = s1[0] + s1[1] + s1[2] + s1[3];
  sq = s2[0] + s2[1] + s2[2] + s2[3];
  float mu = sum * (1.f / D_);
  float rstd = rsqrtf(sq * (1.f / D_) - mu * mu + 1e-6f);
#pragma unroll
  for (int i = 0; i < 8; i++) {
    int idx = t + i * 256;
    outF[(long)row * D_ + idx] = (v[i] - mu) * rstd * g[idx] + b[idx];
  }
}

extern "C" void kernel_launch(void* const* d_in, const int* in_sizes, int n_in,
                              void* d_out, int out_size, void* d_ws, size_t ws_size,
                              hipStream_t stream) {
  const float* x    = (const float*)d_in[0];
  const float* wq   = (const float*)d_in[1];
  const float* wk   = (const float*)d_in[2];
  const float* wv   = (const float*)d_in[3];
  const float* wo   = (const float*)d_in[4];
  const float* rel  = (const float*)d_in[5];
  const float* ln1g = (const float*)d_in[6];
  const float* ln1b = (const float*)d_in[7];
  const float* gw   = (const float*)d_in[8];
  const float* uw   = (const float*)d_in[9];
  const float* dw   = (const float*)d_in[10];
  const float* ln2g = (const float*)d_in[11];
  const float* ln2b = (const float*)d_in[12];
  float* out = (float*)d_out;

  // arena: 8 x MD2 + 4KB (~134.2 MB) — unchanged footprint
  constexpr size_t MD2 = (size_t)M_ * D_ * 2;
  if (ws_size < 8 * MD2 + 4096) return;
  char* w = (char*)d_ws;
  // slot timeline (16.8 MB each):
  //  s0: q          -> attn_out lo -> gwTh (per half)
  //  s1: k          -> attn_out hi -> uwTh (per half)
  //  s2: vT                        -> gch lo
  //  s3: xb -> ctx                 -> gch hi
  //  s4-5: wqT/wkT/wvT -> sc (scores) -> ffn acc (fp32)
  //  s6: h1h (ln1 out, residual for ln2)
  //  s7: woT                       -> dwTh (per half)
  f16* qb   = (f16*)(w + 0 * MD2);
  f16* vT   = (f16*)(w + 2 * MD2);
  f16* xb   = (f16*)(w + 3 * MD2);
  f16* sc   = (f16*)(w + 4 * MD2);
  f16* h1h  = (f16*)(w + 6 * MD2);
  f16* s7   = (f16*)(w + 7 * MD2);
  float* relmean = (float*)(w + 8 * MD2);  // 4 KB tail
  // phase-disjoint aliases
  f16* ctxb = xb;
  float* attn_out = (float*)qb;            // s0-1 fp32 MxD
  f16* wqT  = sc;                          // s4: wqT,wkT,wvT contiguous (25.2MB)
  f16* woT  = s7;
  f16* gwTh = qb;                          // s0
  f16* uwTh = (f16*)(w + 1 * MD2);         // s1
  f16* gch  = vT;                          // s2-3: M x IH f16 (33.6MB)
  f16* dwTh = s7;                          // s7: D x IH f16 (16.8MB)
  float* facc = (float*)sc;                // s4-5: M x D fp32 ffn accumulator

  // --- prep: activation cvt, rel-pos mean, weight transposes (fp32 KxN -> f16 NxK) ---
  cvt_f16_k<<<M_ * D_ / 4 / 256, 256, 0, stream>>>(x, xb, M_ * D_ / 4);
  relmean_k<<<4, 256, 0, stream>>>(rel, relmean);
  transpose_k<<<dim3(32, 32), 256, 0, stream>>>(wq, D_, 0, 0, wqT, D_);
  transpose_k<<<dim3(32, 32), 256, 0, stream>>>(wk, D_, 0, 0, wqT + (size_t)D_ * D_, D_);
  transpose_k<<<dim3(32, 32), 256, 0, stream>>>(wv, D_, 0, 0, wqT + 2 * (size_t)D_ * D_, D_);
  transpose_k<<<dim3(32, 32), 256, 0, stream>>>(wo, D_, 0, 0, woT, D_);

  // --- QKV merged (bz: 0=q, 1=k, 2=v-transposed), f16-NT path ---
  gemm_k<128, 128, 2, 2, OP_QKV><<<dim3(16, 32, 3), 256, 0, stream>>>(
      xb, D_, wqT, D_, qb, D_, D_, 0, nullptr, nullptr);

  // --- attention, 4 chunks of 64 (b,h); f16 scores, softmax in place ---
  for (int c = 0; c < 4; c++) {
    int bh0 = c * 64;
    gemm_k<128, 128, 2, 2, OP_QKT><<<dim3(4, 4, 64), 256, 0, stream>>>(
        qb, D_, qb + (size_t)M_ * D_, D_, sc, S_, HD_, bh0, relmean, nullptr);
    softmax_k<<<64 * S_ / 4, 256, 0, stream>>>(sc);
    gemm_k<64, 64, 2, 2, OP_PV><<<dim3(1, 8, 64), 256, 0, stream>>>(
        sc, S_, vT, S_, ctxb, D_, S_, bh0, nullptr, nullptr);
  }

  // --- output projection + LN1 (f16 residual only; ffn stays fp32 to the end) ---
  gemm_k<128, 128, 2, 2, OP_F32><<<dim3(16, 32, 1), 256, 0, stream>>>(
      ctxb, D_, woT, D_, attn_out, D_, D_, 0, nullptr, nullptr);
  ln1_k<<<M_, 256, 0, stream>>>(x, attn_out, ln1g, ln1b, h1h);

  // --- FFN in two I-halves: JIT weight transposes + fused gate*up + down accum ---
  for (int h = 0; h < 2; h++) {
    transpose_k<<<dim3(32, 64), 256, 0, stream>>>(gw, I_, 0, h * IH_, gwTh, D_);
    transpose_k<<<dim3(32, 64), 256, 0, stream>>>(uw, I_, 0, h * IH_, uwTh, D_);
    transpose_k<<<dim3(64, 32), 256, 0, stream>>>(dw, D_, h * IH_, 0, dwTh, IH_);
    gemm_k<128, 64, 2, 2, OP_GU><<<dim3(IH_ / 64, 32, 1), 256, 0, stream>>>(
        h1h, D_, gwTh, D_, gch, IH_, D_, 0, nullptr, uwTh);
    if (h == 0)
      gemm_k<128, 128, 2, 2, OP_F32><<<dim3(16, 32, 1), 256, 0, stream>>>(
          gch, IH_, dwTh, IH_, facc, D_, IH_, 0, nullptr, nullptr);
    else
      gemm_k<128, 128, 2, 2, OP_ADD><<<dim3(16, 32, 1), 256, 0, stream>>>(
          gch, IH_, dwTh, IH_, facc, D_, IH_, 0, nullptr, nullptr);
  }
  ln2f_k<<<M_, 256, 0, stream>>>(facc, h1h, ln2g, ln2b, out);
}

// Round 2
// 1164.691 us; speedup vs baseline: 1.1215x; 1.0722x over previous
//
#include <hip/hip_runtime.h>
#include <cstdint>
#include <cstddef>

typedef _Float16 f16;
typedef _Float16 f16x8 __attribute__((ext_vector_type(8)));
typedef _Float16 f16x4 __attribute__((ext_vector_type(4)));
typedef float    f32x4 __attribute__((ext_vector_type(4)));

constexpr int S_ = 512, D_ = 2048, H_ = 32, HD_ = 64, I_ = 8192;
constexpr int M_ = 4096;   // B*S
constexpr int IH_ = 4096;  // I/2 (FFN processed in two halves)

enum { OP_F32 = 0, OP_QKT = 3, OP_PV = 4, OP_QKV = 6, OP_GU = 9, OP_ADD = 10 };

__device__ __forceinline__ void gl_lds16(const void* g, void* lds) {
  __builtin_amdgcn_global_load_lds(
      (const __attribute__((address_space(1))) void*)g,
      (__attribute__((address_space(3))) void*)lds, 16, 0, 0);
}

// C = A @ B^T. A f16 MxK row-major, B f16 NxK row-major; both staged via
// global_load_lds (16B/lane, wave-uniform LDS base -> linear layout).
// BK=32: proven m97 layout (16-row regions, no swizzle).
// BK=64: 8-row regions, XOR chunk-swizzle (source-side pre-swizzle + read-side
//        same involution) to avoid the 128B-stride 16-way bank conflict.
// OP_GU: second B (B2) staged into upper half of Bs; epilogue silu(g)*u.
template <int BM, int BN, int WR, int WC, int OP, int BK>
__global__ __launch_bounds__(256, 2) void gemm_k(
    const f16* __restrict__ A, int lda,
    const f16* __restrict__ B, int ldb,
    void* __restrict__ Cp, int ldc,
    int K, int bh0, const float* __restrict__ relmean,
    const f16* __restrict__ B2) {
  static_assert(WR * WC == 4, "4-wave blocks assumed");
  static_assert(BK == 32 || BK == 64, "");
  constexpr bool GU = (OP == OP_GU);
  constexpr int WM = BM / WR, WN = BN / WC;
  constexpr int IM = WM / 16, IN = WN / 16;
  constexpr int RR = (BK == 64) ? 8 : 16;        // rows per 512-f16 staging region
  constexpr int CA = BM * BK / 2048;             // A regions per wave
  constexpr int CB = BN * BK / 2048;             // B regions per wave (per matrix)
  constexpr int KS = BK / 32;                    // MFMA k-subtiles per K-step
  __shared__ __align__(16) f16 As[BM * BK];
  __shared__ __align__(16) f16 Bs[(GU ? 2 : 1) * BN * BK];
  const int tid = threadIdx.x, wave = tid >> 6, lane = tid & 63;
  const int wm = wave / WC, wn = wave % WC;
  const int bn = blockIdx.x, bm = blockIdx.y, bz = blockIdx.z;

  long aoff = 0, boff = 0;
  if constexpr (OP == OP_QKT) {
    int bh = bh0 + bz;
    long hb = (long)(bh >> 5) * (S_ * D_) + (long)(bh & (H_ - 1)) * HD_;
    aoff = hb; boff = hb;
  }
  if constexpr (OP == OP_PV) {
    int bh = bh0 + bz;
    aoff = (long)bz * S_ * S_;       // attn probs, chunk-local
    boff = (long)bh * HD_ * S_;      // vT global
  }
  if constexpr (OP == OP_QKV) boff = (long)bz * D_ * D_;  // wqT/wkT/wvT contiguous

  const f16* Ab = A + aoff + (long)bm * BM * lda;
  const f16* Bb = B + boff + (long)bn * BN * ldb;
  const f16* Bb2 = nullptr;
  if constexpr (GU) Bb2 = B2 + (long)bn * BN * ldb;

  f32x4 acc[IM][IN], acc2[GU ? IM : 1][GU ? IN : 1];
#pragma unroll
  for (int i = 0; i < IM; i++)
#pragma unroll
    for (int j = 0; j < IN; j++) {
      acc[i][j] = {0.f, 0.f, 0.f, 0.f};
      if constexpr (GU) acc2[i][j] = {0.f, 0.f, 0.f, 0.f};
    }

  // staging lane decomposition: RR rows x (BK/8) 16B-chunks per region
  const int lrr = (BK == 64) ? (lane >> 3) : (lane >> 2);
  const int lcc = (BK == 64) ? (lane & 7) : (lane & 3);
  const int scc = (BK == 64) ? (lcc ^ (lrr & 7)) : lcc;  // pre-swizzled source chunk
  const int g = lane >> 4, l15 = lane & 15;

  for (int kt = 0; kt < K; kt += BK) {
    if (kt) __syncthreads();
#pragma unroll
    for (int c = 0; c < CA; c++) {
      int reg = wave * CA + c;               // wave-uniform region id
      gl_lds16(Ab + (long)(reg * RR + lrr) * lda + kt + scc * 8, &As[reg * 512]);
    }
#pragma unroll
    for (int c = 0; c < CB; c++) {
      int reg = wave * CB + c;
      gl_lds16(Bb + (long)(reg * RR + lrr) * ldb + kt + scc * 8, &Bs[reg * 512]);
      if constexpr (GU)
        gl_lds16(Bb2 + (long)(reg * RR + lrr) * ldb + kt + scc * 8,
                 &Bs[BN * BK + reg * 512]);
    }
    __syncthreads();
    f16x8 af[KS][IM], bf[KS][IN], bf2[GU ? KS : 1][GU ? IN : 1];
#pragma unroll
    for (int s = 0; s < KS; s++) {
#pragma unroll
      for (int i = 0; i < IM; i++) {
        int row = wm * WM + i * 16 + l15;
        int cidx = s * 4 + g;
        if constexpr (BK == 64) cidx ^= (row & 7);
        af[s][i] = *(const f16x8*)&As[row * BK + cidx * 8];
      }
#pragma unroll
      for (int j = 0; j < IN; j++) {
        int colL = wn * WN + j * 16 + l15;
        int cidx = s * 4 + g;
        if constexpr (BK == 64) cidx ^= (colL & 7);
        bf[s][j] = *(const f16x8*)&Bs[colL * BK + cidx * 8];
        if constexpr (GU) bf2[s][j] = *(const f16x8*)&Bs[BN * BK + colL * BK + cidx * 8];
      }
    }
#pragma unroll
    for (int s = 0; s < KS; s++)
#pragma unroll
      for (int i = 0; i < IM; i++)
#pragma unroll
        for (int j = 0; j < IN; j++) {
          acc[i][j] = __builtin_amdgcn_mfma_f32_16x16x32_f16(af[s][i], bf[s][j], acc[i][j], 0, 0, 0);
          if constexpr (GU)
            acc2[i][j] = __builtin_amdgcn_mfma_f32_16x16x32_f16(af[s][i], bf2[s][j], acc2[i][j], 0, 0, 0);
        }
  }

  // Epilogue. C/D layout: col = lane&15, row = (lane>>4)*4 + reg  [m89/m91]
  const int r0 = bm * BM + wm * WM + (lane >> 4) * 4;
  const int c0 = bn * BN + wn * WN + l15;
#pragma unroll
  for (int i = 0; i < IM; i++) {
#pragma unroll
    for (int j = 0; j < IN; j++) {
      int rowb = r0 + i * 16;
      int col = c0 + j * 16;
      if constexpr (OP == OP_F32) {
        float* C = (float*)Cp;
#pragma unroll
        for (int t = 0; t < 4; t++) C[(long)(rowb + t) * ldc + col] = acc[i][j][t];
      } else if constexpr (OP == OP_ADD) {
        float* C = (float*)Cp;
#pragma unroll
        for (int t = 0; t < 4; t++) C[(long)(rowb + t) * ldc + col] += acc[i][j][t];
      } else if constexpr (OP == OP_GU) {
        f16* C = (f16*)Cp;
#pragma unroll
        for (int t = 0; t < 4; t++) {
          float gg = acc[i][j][t], u = acc2[i][j][t];
          C[(long)(rowb + t) * ldc + col] = (f16)(gg / (1.f + __expf(-gg)) * u);
        }
      } else if constexpr (OP == OP_QKT) {
        f16* C = (f16*)Cp + (long)bz * S_ * S_;
#pragma unroll
        for (int t = 0; t < 4; t++) {
          int r = rowb + t;
          C[(long)r * S_ + col] = (f16)(acc[i][j][t] * 0.125f + relmean[col - r + 511]);
        }
      } else if constexpr (OP == OP_PV) {
        int bh = bh0 + bz;
        f16* C = (f16*)Cp + (long)(bh >> 5) * (S_ * D_) + (long)(bh & (H_ - 1)) * HD_;
#pragma unroll
        for (int t = 0; t < 4; t++) C[(long)(rowb + t) * ldc + col] = (f16)acc[i][j][t];
      } else if constexpr (OP == OP_QKV) {
        f16* C = (f16*)Cp;
        if (bz < 2) {  // q or k: plain f16 rows
          f16* Cq = C + (long)bz * M_ * D_;
#pragma unroll
          for (int t = 0; t < 4; t++) Cq[(long)(rowb + t) * ldc + col] = (f16)acc[i][j][t];
        } else {       // v: write transposed vT[(b*H+h)*HD+hd][s]
          f16* Cv = C + (long)2 * M_ * D_;
          int b = rowb >> 9, s0 = rowb & 511, h = col >> 6, hd = col & 63;
          f16x4 pk;
#pragma unroll
          for (int t = 0; t < 4; t++) pk[t] = (f16)acc[i][j][t];
          *(f16x4*)&Cv[((long)(b * H_ + h) * HD_ + hd) * S_ + s0] = pk;
        }
      }
    }
  }
}

// fp32 [K][N] column-slice/row-slice -> f16 [Nh][Krows] (N x K, "NT" weight).
// out[n][k] = (f16) in[(k0+k)*ldin + n0+n].  64x64 tiles via LDS.
__global__ __launch_bounds__(256) void transpose_k(
    const float* __restrict__ in, int ldin, int k0, int n0,
    f16* __restrict__ out, int ldout) {
  __shared__ f16 t[64][68];  // stride 68: f16x4-aligned, conflict-lite
  const int kb = blockIdx.x * 64, nb = blockIdx.y * 64;
  const int tid = threadIdx.x;
  {
    const int kr = tid >> 4, nc = (tid & 15) * 4;
    const float* src = in + (long)(k0 + kb) * ldin + (n0 + nb);
#pragma unroll
    for (int i = 0; i < 4; i++) {
      int k = kr + i * 16;
      f32x4 v = *(const f32x4*)&src[(long)k * ldin + nc];
#pragma unroll
      for (int j = 0; j < 4; j++) t[nc + j][k] = (f16)v[j];
    }
  }
  __syncthreads();
  {
    const int n = tid >> 2, kc = (tid & 3) * 16;
    f16* dst = out + (long)(nb + n) * ldout + (kb + kc);
#pragma unroll
    for (int j = 0; j < 4; j++)
      *(f16x4*)&dst[j * 4] = *(const f16x4*)&t[n][kc + j * 4];
  }
}

__global__ void cvt_f16_k(const float* __restrict__ in, f16* __restrict__ out, int n4) {
  int i = blockIdx.x * 256 + threadIdx.x;
  if (i >= n4) return;
  f32x4 v = ((const f32x4*)in)[i];
  f16x4 o;
#pragma unroll
  for (int t = 0; t < 4; t++) o[t] = (f16)v[t];
  ((f16x4*)out)[i] = o;
}

__global__ void relmean_k(const float* __restrict__ rel, float* __restrict__ rm) {
  int i = blockIdx.x * 256 + threadIdx.x;
  if (i >= 1023) return;
  float s = 0.f;
#pragma unroll 8
  for (int d = 0; d < 64; d++) s += rel[i * 64 + d];
  rm[i] = s * (1.f / 64.f);
}

// in-place row softmax over S_=512 f16, one wave per row, f16x8 vector I/O
__global__ __launch_bounds__(256) void softmax_k(f16* __restrict__ Sc) {
  int r = blockIdx.x * 4 + (threadIdx.x >> 6);
  int lane = threadIdx.x & 63;
  f16* s = Sc + (long)r * S_;
  f16x8 d = *(const f16x8*)&s[lane * 8];
  float v[8], mx = -1e30f;
#pragma unroll
  for (int i = 0; i < 8; i++) { v[i] = (float)d[i]; mx = fmaxf(mx, v[i]); }
  for (int off = 32; off; off >>= 1) mx = fmaxf(mx, __shfl_xor(mx, off));
  float sum = 0.f;
#pragma unroll
  for (int i = 0; i < 8; i++) { v[i] = __expf(v[i] - mx); sum += v[i]; }
  for (int off = 32; off; off >>= 1) sum += __shfl_xor(sum, off);
  float rs = 1.f / sum;
  f16x8 o;
#pragma unroll
  for (int i = 0; i < 8; i++) o[i] = (f16)(v[i] * rs);
  *(f16x8*)&s[lane * 8] = o;
}

// h1h = (f16) LN(X + Y) * g + b   (fp32 inputs, f16 out only)
__global__ __launch_bounds__(256) void ln1_k(const float* __restrict__ X,
                                             const float* __restrict__ Y,
                                             const float* __restrict__ g,
                                             const float* __restrict__ b,
                                             f16* __restrict__ outH) {
  int row = blockIdx.x;
  const float* x = X + (long)row * D_;
  const float* y = Y + (long)row * D_;
  int t = threadIdx.x;
  float v[8], sum = 0.f, sq = 0.f;
#pragma unroll
  for (int i = 0; i < 8; i++) {
    int idx = t + i * 256;
    float val = x[idx] + y[idx];
    v[i] = val; sum += val; sq += val * val;
  }
  for (int off = 32; off; off >>= 1) { sum += __shfl_down(sum, off); sq += __shfl_down(sq, off); }
  __shared__ float s1[4], s2[4];
  if ((t & 63) == 0) { s1[t >> 6] = sum; s2[t >> 6] = sq; }
  __syncthreads();
  sum = s1[0] + s1[1] + s1[2] + s1[3];
  sq = s2[0] + s2[1] + s2[2] + s2[3];
  float mu = sum * (1.f / D_);
  float rstd = rsqrtf(sq * (1.f / D_) - mu * mu + 1e-6f);
#pragma unroll
  for (int i = 0; i < 8; i++) {
    int idx = t + i * 256;
    outH[(long)row * D_ + idx] = (f16)((v[i] - mu) * rstd * g[idx] + b[idx]);
  }
}

// out = LN(X + Y) * g + b ; X = ffn accum (fp32), Y = h1h (f16 residual)
__global__ __launch_bounds__(256) void ln2f_k(const float* __restrict__ X,
                                              const f16* __restrict__ Y,
                                              const float* __restrict__ g,
                                              const float* __restrict__ b,
                                              float* __restrict__ outF) {
  int row = blockIdx.x;
  const float* x = X + (long)row * D_;
  const f16* y = Y + (long)row * D_;
  int t = threadIdx.x;
  float v[8], sum = 0.f, sq = 0.f;
#pragma unroll
  for (int i = 0; i < 8; i++) {
    int idx = t + i * 256;
    float val = x[idx] + (float)y[idx];
    v[i] = val; sum += val; sq += val * val;
  }
  for (int off = 32; off; off >>= 1) { sum += __shfl_down(sum, off); sq += __shfl_down(sq, off); }
  __shared__ float s1[4], s2[4];
  if ((t & 63) == 0) { s1[t >> 6] = sum; s2[t >> 6] = sq; }
  __syncthreads();
  sum = s1[0] + s1[1] + s1[2] + s1[3];
  sq = s2[0] + s2[1] + s2[2] + s2[3];
  float mu = sum * (1.f / D_);
  float rstd = rsqrtf(sq * (1.f / D_) - mu * mu + 1e-6f);
#pragma unroll
  for (int i = 0; i < 8; i++) {
    int idx = t + i * 256;
    outF[(long)row * D_ + idx] = (v[i] - mu) * rstd * g[idx] + b[idx];
  }
}

extern "C" void kernel_launch(void* const* d_in, const int* in_sizes, int n_in,
                              void* d_out, int out_size, void* d_ws, size_t ws_size,
                              hipStream_t stream) {
  const float* x    = (const float*)d_in[0];
  const float* wq   = (const float*)d_in[1];
  const float* wk   = (const float*)d_in[2];
  const float* wv   = (const float*)d_in[3];
  const float* wo   = (const float*)d_in[4];
  const float* rel  = (const float*)d_in[5];
  const float* ln1g = (const float*)d_in[6];
  const float* ln1b = (const float*)d_in[7];
  const float* gw   = (const float*)d_in[8];
  const float* uw   = (const float*)d_in[9];
  const float* dw   = (const float*)d_in[10];
  const float* ln2g = (const float*)d_in[11];
  const float* ln2b = (const float*)d_in[12];
  float* out = (float*)d_out;

  // arena: 8 x MD2 + 4KB (~134.2 MB) — unchanged footprint
  constexpr size_t MD2 = (size_t)M_ * D_ * 2;
  if (ws_size < 8 * MD2 + 4096) return;
  char* w = (char*)d_ws;
  // slot timeline (16.8 MB each):
  //  s0: q          -> attn_out lo -> gwTh (per half)
  //  s1: k          -> attn_out hi -> uwTh (per half)
  //  s2: vT                        -> gch lo
  //  s3: xb -> ctx                 -> gch hi
  //  s4-5: wqT/wkT/wvT -> sc (scores) -> ffn acc (fp32)
  //  s6: h1h (ln1 out, residual for ln2)
  //  s7: woT                       -> dwTh (per half)
  f16* qb   = (f16*)(w + 0 * MD2);
  f16* vT   = (f16*)(w + 2 * MD2);
  f16* xb   = (f16*)(w + 3 * MD2);
  f16* sc   = (f16*)(w + 4 * MD2);
  f16* h1h  = (f16*)(w + 6 * MD2);
  f16* s7   = (f16*)(w + 7 * MD2);
  float* relmean = (float*)(w + 8 * MD2);  // 4 KB tail
  // phase-disjoint aliases
  f16* ctxb = xb;
  float* attn_out = (float*)qb;            // s0-1 fp32 MxD
  f16* wqT  = sc;                          // s4: wqT,wkT,wvT contiguous (25.2MB)
  f16* woT  = s7;
  f16* gwTh = qb;                          // s0
  f16* uwTh = (f16*)(w + 1 * MD2);         // s1
  f16* gch  = vT;                          // s2-3: M x IH f16 (33.6MB)
  f16* dwTh = s7;                          // s7: D x IH f16 (16.8MB)
  float* facc = (float*)sc;                // s4-5: M x D fp32 ffn accumulator

  // --- prep: activation cvt, rel-pos mean, weight transposes (fp32 KxN -> f16 NxK) ---
  cvt_f16_k<<<M_ * D_ / 4 / 256, 256, 0, stream>>>(x, xb, M_ * D_ / 4);
  relmean_k<<<4, 256, 0, stream>>>(rel, relmean);
  transpose_k<<<dim3(32, 32), 256, 0, stream>>>(wq, D_, 0, 0, wqT, D_);
  transpose_k<<<dim3(32, 32), 256, 0, stream>>>(wk, D_, 0, 0, wqT + (size_t)D_ * D_, D_);
  transpose_k<<<dim3(32, 32), 256, 0, stream>>>(wv, D_, 0, 0, wqT + 2 * (size_t)D_ * D_, D_);
  transpose_k<<<dim3(32, 32), 256, 0, stream>>>(wo, D_, 0, 0, woT, D_);

  // --- QKV merged (bz: 0=q, 1=k, 2=v-transposed), f16-NT path ---
  gemm_k<128, 128, 2, 2, OP_QKV, 32><<<dim3(16, 32, 3), 256, 0, stream>>>(
      xb, D_, wqT, D_, qb, D_, D_, 0, nullptr, nullptr);

  // --- attention, 4 chunks of 64 (b,h); f16 scores, softmax in place ---
  for (int c = 0; c < 4; c++) {
    int bh0 = c * 64;
    gemm_k<128, 128, 2, 2, OP_QKT, 64><<<dim3(4, 4, 64), 256, 0, stream>>>(
        qb, D_, qb + (size_t)M_ * D_, D_, sc, S_, HD_, bh0, relmean, nullptr);
    softmax_k<<<64 * S_ / 4, 256, 0, stream>>>(sc);
    gemm_k<64, 64, 2, 2, OP_PV, 64><<<dim3(1, 8, 64), 256, 0, stream>>>(
        sc, S_, vT, S_, ctxb, D_, S_, bh0, nullptr, nullptr);
  }

  // --- output projection + LN1 (f16 residual only; ffn stays fp32 to the end) ---
  gemm_k<128, 128, 2, 2, OP_F32, 32><<<dim3(16, 32, 1), 256, 0, stream>>>(
      ctxb, D_, woT, D_, attn_out, D_, D_, 0, nullptr, nullptr);
  ln1_k<<<M_, 256, 0, stream>>>(x, attn_out, ln1g, ln1b, h1h);

  // --- FFN in two I-halves: JIT weight transposes + fused gate*up + down accum ---
  for (int h = 0; h < 2; h++) {
    transpose_k<<<dim3(32, 64), 256, 0, stream>>>(gw, I_, 0, h * IH_, gwTh, D_);
    transpose_k<<<dim3(32, 64), 256, 0, stream>>>(uw, I_, 0, h * IH_, uwTh, D_);
    transpose_k<<<dim3(64, 32), 256, 0, stream>>>(dw, D_, h * IH_, 0, dwTh, IH_);
    gemm_k<128, 128, 2, 2, OP_GU, 32><<<dim3(IH_ / 128, 32, 1), 256, 0, stream>>>(
        h1h, D_, gwTh, D_, gch, IH_, D_, 0, nullptr, uwTh);
    if (h == 0)
      gemm_k<128, 128, 2, 2, OP_F32, 32><<<dim3(16, 32, 1), 256, 0, stream>>>(
          gch, IH_, dwTh, IH_, facc, D_, IH_, 0, nullptr, nullptr);
    else
      gemm_k<128, 128, 2, 2, OP_ADD, 32><<<dim3(16, 32, 1), 256, 0, stream>>>(
          gch, IH_, dwTh, IH_, facc, D_, IH_, 0, nullptr, nullptr);
  }
  ln2f_k<<<M_, 256, 0, stream>>>(facc, h1h, ln2g, ln2b, out);
}

// Round 3
// 1086.113 us; speedup vs baseline: 1.2026x; 1.0723x over previous
//
#include <hip/hip_runtime.h>
#include <cstdint>
#include <cstddef>

typedef _Float16 f16;
typedef _Float16 f16x8 __attribute__((ext_vector_type(8)));
typedef _Float16 f16x4 __attribute__((ext_vector_type(4)));
typedef float    f32x4 __attribute__((ext_vector_type(4)));

constexpr int S_ = 512, D_ = 2048, H_ = 32, HD_ = 64, I_ = 8192;
constexpr int M_ = 4096;   // B*S
constexpr int IH_ = 4096;  // I/2 (FFN processed in two halves)

enum { OP_F32 = 0, OP_QKT = 3, OP_PV = 4, OP_QKV = 6, OP_GU = 9, OP_ADD = 10 };

__device__ __forceinline__ void gl_lds16(const void* g, void* lds) {
  __builtin_amdgcn_global_load_lds(
      (const __attribute__((address_space(1))) void*)g,
      (__attribute__((address_space(3))) void*)lds, 16, 0, 0);
}

// C = A @ B^T. A f16 MxK row-major, B f16 NxK row-major; both staged via
// global_load_lds (16B/lane, wave-uniform LDS base -> linear layout).
// BK=32: proven m97 layout (16-row regions, no swizzle).
// BK=64: 8-row regions, XOR chunk-swizzle (source-side pre-swizzle + read-side
//        same involution) to avoid the 128B-stride 16-way bank conflict.
// OP_GU: second B (B2) staged into upper half of Bs; epilogue silu(g)*u.
template <int BM, int BN, int WR, int WC, int OP, int BK>
__global__ __launch_bounds__(256, 2) void gemm_k(
    const f16* __restrict__ A, int lda,
    const f16* __restrict__ B, int ldb,
    void* __restrict__ Cp, int ldc,
    int K, int bh0, const float* __restrict__ relmean,
    const f16* __restrict__ B2) {
  static_assert(WR * WC == 4, "4-wave blocks assumed");
  static_assert(BK == 32 || BK == 64, "");
  constexpr bool GU = (OP == OP_GU);
  constexpr int WM = BM / WR, WN = BN / WC;
  constexpr int IM = WM / 16, IN = WN / 16;
  constexpr int RR = (BK == 64) ? 8 : 16;        // rows per 512-f16 staging region
  constexpr int CA = BM * BK / 2048;             // A regions per wave
  constexpr int CB = BN * BK / 2048;             // B regions per wave (per matrix)
  constexpr int KS = BK / 32;                    // MFMA k-subtiles per K-step
  __shared__ __align__(16) f16 As[BM * BK];
  __shared__ __align__(16) f16 Bs[(GU ? 2 : 1) * BN * BK];
  const int tid = threadIdx.x, wave = tid >> 6, lane = tid & 63;
  const int wm = wave / WC, wn = wave % WC;
  const int bn = blockIdx.x, bm = blockIdx.y, bz = blockIdx.z;

  long aoff = 0, boff = 0;
  if constexpr (OP == OP_QKT) {
    int bh = bh0 + bz;
    long hb = (long)(bh >> 5) * (S_ * D_) + (long)(bh & (H_ - 1)) * HD_;
    aoff = hb; boff = hb;
  }
  if constexpr (OP == OP_PV) {
    int bh = bh0 + bz;
    aoff = (long)bz * S_ * S_;       // attn probs, chunk-local
    boff = (long)bh * HD_ * S_;      // vT global
  }
  if constexpr (OP == OP_QKV) boff = (long)bz * D_ * D_;  // wqT/wkT/wvT contiguous

  const f16* Ab = A + aoff + (long)bm * BM * lda;
  const f16* Bb = B + boff + (long)bn * BN * ldb;
  const f16* Bb2 = nullptr;
  if constexpr (GU) Bb2 = B2 + (long)bn * BN * ldb;

  f32x4 acc[IM][IN], acc2[GU ? IM : 1][GU ? IN : 1];
#pragma unroll
  for (int i = 0; i < IM; i++)
#pragma unroll
    for (int j = 0; j < IN; j++) {
      acc[i][j] = {0.f, 0.f, 0.f, 0.f};
      if constexpr (GU) acc2[i][j] = {0.f, 0.f, 0.f, 0.f};
    }

  // staging lane decomposition: RR rows x (BK/8) 16B-chunks per region
  const int lrr = (BK == 64) ? (lane >> 3) : (lane >> 2);
  const int lcc = (BK == 64) ? (lane & 7) : (lane & 3);
  const int scc = (BK == 64) ? (lcc ^ (lrr & 7)) : lcc;  // pre-swizzled source chunk
  const int g = lane >> 4, l15 = lane & 15;

  for (int kt = 0; kt < K; kt += BK) {
    if (kt) __syncthreads();
#pragma unroll
    for (int c = 0; c < CA; c++) {
      int reg = wave * CA + c;               // wave-uniform region id
      gl_lds16(Ab + (long)(reg * RR + lrr) * lda + kt + scc * 8, &As[reg * 512]);
    }
#pragma unroll
    for (int c = 0; c < CB; c++) {
      int reg = wave * CB + c;
      gl_lds16(Bb + (long)(reg * RR + lrr) * ldb + kt + scc * 8, &Bs[reg * 512]);
      if constexpr (GU)
        gl_lds16(Bb2 + (long)(reg * RR + lrr) * ldb + kt + scc * 8,
                 &Bs[BN * BK + reg * 512]);
    }
    __syncthreads();
    f16x8 af[KS][IM], bf[KS][IN], bf2[GU ? KS : 1][GU ? IN : 1];
#pragma unroll
    for (int s = 0; s < KS; s++) {
#pragma unroll
      for (int i = 0; i < IM; i++) {
        int row = wm * WM + i * 16 + l15;
        int cidx = s * 4 + g;
        if constexpr (BK == 64) cidx ^= (row & 7);
        af[s][i] = *(const f16x8*)&As[row * BK + cidx * 8];
      }
#pragma unroll
      for (int j = 0; j < IN; j++) {
        int colL = wn * WN + j * 16 + l15;
        int cidx = s * 4 + g;
        if constexpr (BK == 64) cidx ^= (colL & 7);
        bf[s][j] = *(const f16x8*)&Bs[colL * BK + cidx * 8];
        if constexpr (GU) bf2[s][j] = *(const f16x8*)&Bs[BN * BK + colL * BK + cidx * 8];
      }
    }
#pragma unroll
    for (int s = 0; s < KS; s++)
#pragma unroll
      for (int i = 0; i < IM; i++)
#pragma unroll
        for (int j = 0; j < IN; j++) {
          acc[i][j] = __builtin_amdgcn_mfma_f32_16x16x32_f16(af[s][i], bf[s][j], acc[i][j], 0, 0, 0);
          if constexpr (GU)
            acc2[i][j] = __builtin_amdgcn_mfma_f32_16x16x32_f16(af[s][i], bf2[s][j], acc2[i][j], 0, 0, 0);
        }
  }

  // Epilogue. C/D layout: col = lane&15, row = (lane>>4)*4 + reg  [m89/m91]
  const int r0 = bm * BM + wm * WM + (lane >> 4) * 4;
  const int c0 = bn * BN + wn * WN + l15;
#pragma unroll
  for (int i = 0; i < IM; i++) {
#pragma unroll
    for (int j = 0; j < IN; j++) {
      int rowb = r0 + i * 16;
      int col = c0 + j * 16;
      if constexpr (OP == OP_F32) {
        float* C = (float*)Cp;
#pragma unroll
        for (int t = 0; t < 4; t++) C[(long)(rowb + t) * ldc + col] = acc[i][j][t];
      } else if constexpr (OP == OP_ADD) {
        float* C = (float*)Cp;
#pragma unroll
        for (int t = 0; t < 4; t++) C[(long)(rowb + t) * ldc + col] += acc[i][j][t];
      } else if constexpr (OP == OP_GU) {
        f16* C = (f16*)Cp;
#pragma unroll
        for (int t = 0; t < 4; t++) {
          float gg = acc[i][j][t], u = acc2[i][j][t];
          C[(long)(rowb + t) * ldc + col] = (f16)(gg / (1.f + __expf(-gg)) * u);
        }
      } else if constexpr (OP == OP_QKT) {
        f16* C = (f16*)Cp + (long)bz * S_ * S_;
#pragma unroll
        for (int t = 0; t < 4; t++) {
          int r = rowb + t;
          C[(long)r * S_ + col] = (f16)(acc[i][j][t] * 0.125f + relmean[col - r + 511]);
        }
      } else if constexpr (OP == OP_PV) {
        int bh = bh0 + bz;
        f16* C = (f16*)Cp + (long)(bh >> 5) * (S_ * D_) + (long)(bh & (H_ - 1)) * HD_;
#pragma unroll
        for (int t = 0; t < 4; t++) C[(long)(rowb + t) * ldc + col] = (f16)acc[i][j][t];
      } else if constexpr (OP == OP_QKV) {
        f16* C = (f16*)Cp;
        if (bz < 2) {  // q or k: plain f16 rows
          f16* Cq = C + (long)bz * M_ * D_;
#pragma unroll
          for (int t = 0; t < 4; t++) Cq[(long)(rowb + t) * ldc + col] = (f16)acc[i][j][t];
        } else {       // v: write transposed vT[(b*H+h)*HD+hd][s]
          f16* Cv = C + (long)2 * M_ * D_;
          int b = rowb >> 9, s0 = rowb & 511, h = col >> 6, hd = col & 63;
          f16x4 pk;
#pragma unroll
          for (int t = 0; t < 4; t++) pk[t] = (f16)acc[i][j][t];
          *(f16x4*)&Cv[((long)(b * H_ + h) * HD_ + hd) * S_ + s0] = pk;
        }
      }
    }
  }
}

// Fused attention: per block = one (bh, 128-row q-tile). 8 waves, 512 threads.
// LDS: K 512x64 (64KB, XOR-swizzled chunks), V^T 64x512 (64KB, swizzled),
// relmean 4KB. After QKT, each wave's P^T (16 q x 512 s, f16) overwrites its
// 8KB slice of the K area, one 256-s half at a time.
__global__ __launch_bounds__(512, 2) void fattn_k(
    const f16* __restrict__ Q, const f16* __restrict__ Kg,
    const f16* __restrict__ Vt, f16* __restrict__ Ctx,
    const float* __restrict__ rel) {
  __shared__ __align__(16) f16 Ks[512 * 64];
  __shared__ __align__(16) f16 Vs[64 * 512];
  __shared__ float rms[1024];
  const int tid = threadIdx.x, wave = tid >> 6, lane = tid & 63;
  const int g = lane >> 4, l15 = lane & 15;
  const int lrr = lane >> 3, lcc = lane & 7;
  const int bm = blockIdx.x, bh = blockIdx.y;
  const int b = bh >> 5, h = bh & 31;
  const long qrow0 = (long)b * S_ + bm * 128;  // global M-row of q-tile start
  const long krow0 = (long)b * S_;
  const int hoff = h * HD_;

  // stage K: 64 regions of 8 rows x 64k; source chunk pre-swizzled lcc^lrr
#pragma unroll
  for (int c = 0; c < 8; c++) {
    int reg = wave * 8 + c;
    gl_lds16(Kg + (krow0 + reg * 8 + lrr) * D_ + hoff + (lcc ^ lrr) * 8,
             &Ks[reg * 512]);
  }
  // stage V^T: 64 regions = (hd-rowblock rb, s-colchunk cb) of 8x64
  const f16* vb = Vt + (long)bh * HD_ * S_;
#pragma unroll
  for (int c = 0; c < 8; c++) {
    int reg = wave * 8 + c;
    int rb = reg >> 3, cb = reg & 7;
    gl_lds16(vb + (long)(rb * 8 + lrr) * S_ + cb * 64 + (lcc ^ lrr) * 8,
             &Vs[reg * 512]);
  }
  for (int i = tid; i < 1023; i += 512) rms[i] = rel[i];

  // Q fragments: direct global->reg (16 q-rows per wave)
  f16x8 aq[2];
#pragma unroll
  for (int ks = 0; ks < 2; ks++)
    aq[ks] = *(const f16x8*)&Q[(qrow0 + wave * 16 + l15) * D_ + hoff + ks * 32 + g * 8];

  __syncthreads();

  // QK^T: wave computes 16 q-rows x 512 s-cols
  f32x4 acc[32];
#pragma unroll
  for (int jn = 0; jn < 32; jn++) acc[jn] = {0.f, 0.f, 0.f, 0.f};
#pragma unroll
  for (int jn = 0; jn < 32; jn++) {
    int r = jn * 16 + l15;
    f16x8 b0 = *(const f16x8*)&Ks[r * 64 + ((g) ^ (r & 7)) * 8];
    f16x8 b1 = *(const f16x8*)&Ks[r * 64 + ((4 + g) ^ (r & 7)) * 8];
    acc[jn] = __builtin_amdgcn_mfma_f32_16x16x32_f16(aq[0], b0, acc[jn], 0, 0, 0);
    acc[jn] = __builtin_amdgcn_mfma_f32_16x16x32_f16(aq[1], b1, acc[jn], 0, 0, 0);
  }

  // bias + row softmax (rows q = g*4+t held across the 16-lane l15 group)
  const int qr0 = bm * 128 + wave * 16 + g * 4;  // within-S q row (t=0)
  float mx[4] = {-1e30f, -1e30f, -1e30f, -1e30f}, sum[4] = {0.f, 0.f, 0.f, 0.f};
#pragma unroll
  for (int t = 0; t < 4; t++) {
    int bb = l15 - (qr0 + t) + 511;
#pragma unroll
    for (int jn = 0; jn < 32; jn++) {
      float v = acc[jn][t] * 0.125f + rms[bb + jn * 16];
      acc[jn][t] = v;
      mx[t] = fmaxf(mx[t], v);
    }
  }
#pragma unroll
  for (int off = 8; off; off >>= 1)
#pragma unroll
    for (int t = 0; t < 4; t++) mx[t] = fmaxf(mx[t], __shfl_xor(mx[t], off));
#pragma unroll
  for (int t = 0; t < 4; t++)
#pragma unroll
    for (int jn = 0; jn < 32; jn++) {
      float e = __expf(acc[jn][t] - mx[t]);
      acc[jn][t] = e;
      sum[t] += e;
    }
#pragma unroll
  for (int off = 8; off; off >>= 1)
#pragma unroll
    for (int t = 0; t < 4; t++) sum[t] += __shfl_xor(sum[t], off);
  float rs[4];
#pragma unroll
  for (int t = 0; t < 4; t++) rs[t] = 1.f / sum[t];

  __syncthreads();  // all waves done reading Ks; safe to overwrite with P^T

  // PV in two 256-s halves. P^T[s][q] in wave-private 8KB slice of Ks area.
  f16* Pb = &Ks[wave * 4096];
  f32x4 aco[4];
#pragma unroll
  for (int jv = 0; jv < 4; jv++) aco[jv] = {0.f, 0.f, 0.f, 0.f};
#pragma unroll
  for (int hh = 0; hh < 2; hh++) {
#pragma unroll
    for (int jl = 0; jl < 16; jl++) {
      int jn = hh * 16 + jl;
      f16x4 w;
#pragma unroll
      for (int t = 0; t < 4; t++) w[t] = (f16)(acc[jn][t] * rs[t]);
      *(f16x4*)&Pb[(jl * 16 + l15) * 16 + g * 4] = w;  // P^T[s_local][q=g*4+t]
    }
#pragma unroll
    for (int kl = 0; kl < 8; kl++) {
      f16x8 ap;
#pragma unroll
      for (int i = 0; i < 8; i++)
        ap[i] = Pb[(kl * 32 + g * 8 + i) * 16 + l15];  // P[q=l15][s]
#pragma unroll
      for (int jv = 0; jv < 4; jv++) {
        int r = jv * 16 + l15, c = (hh * 8 + kl) * 4 + g;
        f16x8 bv = *(const f16x8*)&Vs[(r >> 3) * 4096 + (c >> 3) * 512 +
                                      (r & 7) * 64 + ((c & 7) ^ (r & 7)) * 8];
        aco[jv] = __builtin_amdgcn_mfma_f32_16x16x32_f16(ap, bv, aco[jv], 0, 0, 0);
      }
    }
  }

  // epilogue: ctx rows qrow0 + wave*16 + g*4 + t, cols hoff + jv*16 + l15
#pragma unroll
  for (int jv = 0; jv < 4; jv++)
#pragma unroll
    for (int t = 0; t < 4; t++)
      Ctx[(qrow0 + wave * 16 + g * 4 + t) * D_ + hoff + jv * 16 + l15] =
          (f16)aco[jv][t];
}

// fp32 [K][N] column-slice/row-slice -> f16 [Nh][Krows] (N x K, "NT" weight).
// out[n][k] = (f16) in[(k0+k)*ldin + n0+n].  64x64 tiles via LDS.
__global__ __launch_bounds__(256) void transpose_k(
    const float* __restrict__ in, int ldin, int k0, int n0,
    f16* __restrict__ out, int ldout) {
  __shared__ f16 t[64][68];  // stride 68: f16x4-aligned, conflict-lite
  const int kb = blockIdx.x * 64, nb = blockIdx.y * 64;
  const int tid = threadIdx.x;
  {
    const int kr = tid >> 4, nc = (tid & 15) * 4;
    const float* src = in + (long)(k0 + kb) * ldin + (n0 + nb);
#pragma unroll
    for (int i = 0; i < 4; i++) {
      int k = kr + i * 16;
      f32x4 v = *(const f32x4*)&src[(long)k * ldin + nc];
#pragma unroll
      for (int j = 0; j < 4; j++) t[nc + j][k] = (f16)v[j];
    }
  }
  __syncthreads();
  {
    const int n = tid >> 2, kc = (tid & 3) * 16;
    f16* dst = out + (long)(nb + n) * ldout + (kb + kc);
#pragma unroll
    for (int j = 0; j < 4; j++)
      *(f16x4*)&dst[j * 4] = *(const f16x4*)&t[n][kc + j * 4];
  }
}

__global__ void cvt_f16_k(const float* __restrict__ in, f16* __restrict__ out, int n4) {
  int i = blockIdx.x * 256 + threadIdx.x;
  if (i >= n4) return;
  f32x4 v = ((const f32x4*)in)[i];
  f16x4 o;
#pragma unroll
  for (int t = 0; t < 4; t++) o[t] = (f16)v[t];
  ((f16x4*)out)[i] = o;
}

__global__ void relmean_k(const float* __restrict__ rel, float* __restrict__ rm) {
  int i = blockIdx.x * 256 + threadIdx.x;
  if (i >= 1023) return;
  float s = 0.f;
#pragma unroll 8
  for (int d = 0; d < 64; d++) s += rel[i * 64 + d];
  rm[i] = s * (1.f / 64.f);
}

// h1h = (f16) LN(X + Y) * g + b   (fp32 inputs, f16 out only)
__global__ __launch_bounds__(256) void ln1_k(const float* __restrict__ X,
                                             const float* __restrict__ Y,
                                             const float* __restrict__ g,
                                             const float* __restrict__ b,
                                             f16* __restrict__ outH) {
  int row = blockIdx.x;
  const float* x = X + (long)row * D_;
  const float* y = Y + (long)row * D_;
  int t = threadIdx.x;
  float v[8], sum = 0.f, sq = 0.f;
#pragma unroll
  for (int i = 0; i < 8; i++) {
    int idx = t + i * 256;
    float val = x[idx] + y[idx];
    v[i] = val; sum += val; sq += val * val;
  }
  for (int off = 32; off; off >>= 1) { sum += __shfl_down(sum, off); sq += __shfl_down(sq, off); }
  __shared__ float s1[4], s2[4];
  if ((t & 63) == 0) { s1[t >> 6] = sum; s2[t >> 6] = sq; }
  __syncthreads();
  sum = s1[0] + s1[1] + s1[2] + s1[3];
  sq = s2[0] + s2[1] + s2[2] + s2[3];
  float mu = sum * (1.f / D_);
  float rstd = rsqrtf(sq * (1.f / D_) - mu * mu + 1e-6f);
#pragma unroll
  for (int i = 0; i < 8; i++) {
    int idx = t + i * 256;
    outH[(long)row * D_ + idx] = (f16)((v[i] - mu) * rstd * g[idx] + b[idx]);
  }
}

// out = LN(X + Y) * g + b ; X = ffn accum (fp32), Y = h1h (f16 residual)
__global__ __launch_bounds__(256) void ln2f_k(const float* __restrict__ X,
                                              const f16* __restrict__ Y,
                                              const float* __restrict__ g,
                                              const float* __restrict__ b,
                                              float* __restrict__ outF) {
  int row = blockIdx.x;
  const float* x = X + (long)row * D_;
  const f16* y = Y + (long)row * D_;
  int t = threadIdx.x;
  float v[8], sum = 0.f, sq = 0.f;
#pragma unroll
  for (int i = 0; i < 8; i++) {
    int idx = t + i * 256;
    float val = x[idx] + (float)y[idx];
    v[i] = val; sum += val; sq += val * val;
  }
  for (int off = 32; off; off >>= 1) { sum += __shfl_down(sum, off); sq += __shfl_down(sq, off); }
  __shared__ float s1[4], s2[4];
  if ((t & 63) == 0) { s1[t >> 6] = sum; s2[t >> 6] = sq; }
  __syncthreads();
  sum = s1[0] + s1[1] + s1[2] + s1[3];
  sq = s2[0] + s2[1] + s2[2] + s2[3];
  float mu = sum * (1.f / D_);
  float rstd = rsqrtf(sq * (1.f / D_) - mu * mu + 1e-6f);
#pragma unroll
  for (int i = 0; i < 8; i++) {
    int idx = t + i * 256;
    outF[(long)row * D_ + idx] = (v[i] - mu) * rstd * g[idx] + b[idx];
  }
}

extern "C" void kernel_launch(void* const* d_in, const int* in_sizes, int n_in,
                              void* d_out, int out_size, void* d_ws, size_t ws_size,
                              hipStream_t stream) {
  const float* x    = (const float*)d_in[0];
  const float* wq   = (const float*)d_in[1];
  const float* wk   = (const float*)d_in[2];
  const float* wv   = (const float*)d_in[3];
  const float* wo   = (const float*)d_in[4];
  const float* rel  = (const float*)d_in[5];
  const float* ln1g = (const float*)d_in[6];
  const float* ln1b = (const float*)d_in[7];
  const float* gw   = (const float*)d_in[8];
  const float* uw   = (const float*)d_in[9];
  const float* dw   = (const float*)d_in[10];
  const float* ln2g = (const float*)d_in[11];
  const float* ln2b = (const float*)d_in[12];
  float* out = (float*)d_out;

  // arena: 8 x MD2 + 4KB (~134.2 MB) — unchanged footprint
  constexpr size_t MD2 = (size_t)M_ * D_ * 2;
  if (ws_size < 8 * MD2 + 4096) return;
  char* w = (char*)d_ws;
  // slot timeline (16.8 MB each):
  //  s0: q          -> attn_out lo -> gwTh (per half)
  //  s1: k          -> attn_out hi -> uwTh (per half)
  //  s2: vT                        -> gch lo
  //  s3: xb -> ctx                 -> gch hi
  //  s4-5: wqT/wkT/wvT             -> ffn acc (fp32)
  //  s6: h1h (ln1 out, residual for ln2)
  //  s7: woT                       -> dwTh (per half)
  f16* qb   = (f16*)(w + 0 * MD2);
  f16* vT   = (f16*)(w + 2 * MD2);
  f16* xb   = (f16*)(w + 3 * MD2);
  f16* s45  = (f16*)(w + 4 * MD2);
  f16* h1h  = (f16*)(w + 6 * MD2);
  f16* s7   = (f16*)(w + 7 * MD2);
  float* relmean = (float*)(w + 8 * MD2);  // 4 KB tail
  // phase-disjoint aliases
  f16* ctxb = xb;
  float* attn_out = (float*)qb;            // s0-1 fp32 MxD
  f16* wqT  = s45;                         // s4: wqT,wkT,wvT contiguous (25.2MB)
  f16* woT  = s7;
  f16* gwTh = qb;                          // s0
  f16* uwTh = (f16*)(w + 1 * MD2);         // s1
  f16* gch  = vT;                          // s2-3: M x IH f16 (33.6MB)
  f16* dwTh = s7;                          // s7: D x IH f16 (16.8MB)
  float* facc = (float*)s45;               // s4-5: M x D fp32 ffn accumulator

  // --- prep: activation cvt, rel-pos mean, weight transposes (fp32 KxN -> f16 NxK) ---
  cvt_f16_k<<<M_ * D_ / 4 / 256, 256, 0, stream>>>(x, xb, M_ * D_ / 4);
  relmean_k<<<4, 256, 0, stream>>>(rel, relmean);
  transpose_k<<<dim3(32, 32), 256, 0, stream>>>(wq, D_, 0, 0, wqT, D_);
  transpose_k<<<dim3(32, 32), 256, 0, stream>>>(wk, D_, 0, 0, wqT + (size_t)D_ * D_, D_);
  transpose_k<<<dim3(32, 32), 256, 0, stream>>>(wv, D_, 0, 0, wqT + 2 * (size_t)D_ * D_, D_);
  transpose_k<<<dim3(32, 32), 256, 0, stream>>>(wo, D_, 0, 0, woT, D_);

  // --- QKV merged (bz: 0=q, 1=k, 2=v-transposed), f16-NT path ---
  gemm_k<128, 128, 2, 2, OP_QKV, 32><<<dim3(16, 32, 3), 256, 0, stream>>>(
      xb, D_, wqT, D_, qb, D_, D_, 0, nullptr, nullptr);

  // --- fused attention: QK^T + bias + softmax + PV in one kernel ---
  fattn_k<<<dim3(4, 256), 512, 0, stream>>>(
      qb, qb + (size_t)M_ * D_, vT, ctxb, relmean);

  // --- output projection + LN1 (f16 residual only; ffn stays fp32 to the end) ---
  gemm_k<128, 128, 2, 2, OP_F32, 32><<<dim3(16, 32, 1), 256, 0, stream>>>(
      ctxb, D_, woT, D_, attn_out, D_, D_, 0, nullptr, nullptr);
  ln1_k<<<M_, 256, 0, stream>>>(x, attn_out, ln1g, ln1b, h1h);

  // --- FFN in two I-halves: JIT weight transposes + fused gate*up + down accum ---
  for (int h = 0; h < 2; h++) {
    transpose_k<<<dim3(32, 64), 256, 0, stream>>>(gw, I_, 0, h * IH_, gwTh, D_);
    transpose_k<<<dim3(32, 64), 256, 0, stream>>>(uw, I_, 0, h * IH_, uwTh, D_);
    transpose_k<<<dim3(64, 32), 256, 0, stream>>>(dw, D_, h * IH_, 0, dwTh, IH_);
    gemm_k<128, 128, 2, 2, OP_GU, 32><<<dim3(IH_ / 128, 32, 1), 256, 0, stream>>>(
        h1h, D_, gwTh, D_, gch, IH_, D_, 0, nullptr, uwTh);
    if (h == 0)
      gemm_k<128, 128, 2, 2, OP_F32, 32><<<dim3(16, 32, 1), 256, 0, stream>>>(
          gch, IH_, dwTh, IH_, facc, D_, IH_, 0, nullptr, nullptr);
    else
      gemm_k<128, 128, 2, 2, OP_ADD, 32><<<dim3(16, 32, 1), 256, 0, stream>>>(
          gch, IH_, dwTh, IH_, facc, D_, IH_, 0, nullptr, nullptr);
  }
  ln2f_k<<<M_, 256, 0, stream>>>(facc, h1h, ln2g, ln2b, out);
}

// Round 4
// 1054.255 us; speedup vs baseline: 1.2390x; 1.0302x over previous
//
#include <hip/hip_runtime.h>
#include <cstdint>
#include <cstddef>

typedef _Float16 f16;
typedef _Float16 f16x8 __attribute__((ext_vector_type(8)));
typedef _Float16 f16x4 __attribute__((ext_vector_type(4)));
typedef float    f32x4 __attribute__((ext_vector_type(4)));

constexpr int S_ = 512, D_ = 2048, H_ = 32, HD_ = 64, I_ = 8192;
constexpr int M_ = 4096;   // B*S
constexpr int IH_ = 4096;  // I/2 (FFN processed in two halves)

enum { OP_F32 = 0, OP_QKT = 3, OP_PV = 4, OP_QKV = 6, OP_GU = 9, OP_ADD = 10,
       OP_SILU = 11, OP_UPG = 12 };

__device__ __forceinline__ void gl_lds16(const void* g, void* lds) {
  __builtin_amdgcn_global_load_lds(
      (const __attribute__((address_space(1))) void*)g,
      (__attribute__((address_space(3))) void*)lds, 16, 0, 0);
}

// ======================= 8-phase 256x256 f16 NT GEMM =======================
// C = A @ B^T, A f16 MxK row-major, B f16 NxK row-major. BK=64, 8 waves
// (2M x 4N), per-wave 128x64 output. LDS 128KB: [buf][half] 128x64 halves for
// A and B, double-buffered. st_16x32 swizzle (byte ^= ((byte>>9)&1)<<5) via
// pre-swizzled global source (linear global_load_lds dest) + same involution
// on ds_read chunks. Counted vmcnt(4) once per K-tile; setprio around MFMA.
template <int MH, int NH>
__device__ __forceinline__ void mfma_q(f32x4 (&acc)[8][4],
                                       const f16x8 (&ra)[2][4],
                                       const f16x8 (&rb)[2][2]) {
#pragma unroll
  for (int ks = 0; ks < 2; ks++)
#pragma unroll
    for (int i = 0; i < 4; i++)
#pragma unroll
      for (int j = 0; j < 2; j++)
        acc[MH * 4 + i][NH * 2 + j] = __builtin_amdgcn_mfma_f32_16x16x32_f16(
            ra[ks][i], rb[ks][j], acc[MH * 4 + i][NH * 2 + j], 0, 0, 0);
}

template <int OP>
__global__ __launch_bounds__(512, 2) void gemm8_k(
    const f16* __restrict__ A, int lda,
    const f16* __restrict__ B, int ldb,
    void* __restrict__ Cp, int ldc, int K,
    const f16* __restrict__ G) {
  __shared__ __align__(16) f16 As[2 * 2 * 128 * 64];  // 64KB
  __shared__ __align__(16) f16 Bs[2 * 2 * 128 * 64];  // 64KB
  const int tid = threadIdx.x, wave = tid >> 6, lane = tid & 63;
  const int wm = wave >> 2, wn = wave & 3;
  const int g = lane >> 4, l15 = lane & 15;
  const int lr8 = lane >> 3, lc8 = lane & 7;
  const int bn = blockIdx.x, bm = blockIdx.y;
  const f16* Ab = A + (long)bm * 256 * lda;
  const f16* Bb = B + (long)bn * 256 * ldb;
  // stage: dest byte = region*1024 + lane*16 -> bit9 = (lane>>5)&1
  const int sc_src = lc8 ^ (((lr8 >> 2) & 1) << 1);
  // read: row bits 0-3 = l15 -> bit9 of byte = (l15>>2)&1
  const int swz_rd = ((l15 >> 2) & 1) << 1;

  f32x4 acc[8][4];
#pragma unroll
  for (int i = 0; i < 8; i++)
#pragma unroll
    for (int j = 0; j < 4; j++) acc[i][j] = {0.f, 0.f, 0.f, 0.f};

  int aoff[2][4], boff[2][2];
#pragma unroll
  for (int ks = 0; ks < 2; ks++) {
#pragma unroll
    for (int i = 0; i < 4; i++)
      aoff[ks][i] = (i * 16 + l15) * 64 + ((ks * 4 + g) ^ swz_rd) * 8;
#pragma unroll
    for (int j = 0; j < 2; j++)
      boff[ks][j] = ((wn & 1) * 64 + j * 16 + l15) * 64 + ((ks * 4 + g) ^ swz_rd) * 8;
  }

  auto stA = [&](int buf, int half, int kt) {
#pragma unroll
    for (int c = 0; c < 2; c++)
      gl_lds16(Ab + (long)(half * 128 + (wave * 2 + c) * 8 + lr8) * lda + kt + sc_src * 8,
               &As[buf * 16384 + half * 8192 + (wave * 2 + c) * 512]);
  };
  auto stB = [&](int buf, int half, int kt) {
#pragma unroll
    for (int c = 0; c < 2; c++)
      gl_lds16(Bb + (long)(half * 128 + (wave * 2 + c) * 8 + lr8) * ldb + kt + sc_src * 8,
               &Bs[buf * 16384 + half * 8192 + (wave * 2 + c) * 512]);
  };

  const int NT = K / 64;
  // prologue: B0(0) B1(0) A0(0) A1(0) B0(1) B1(1) = 12 loads; retire tile0.
  stB(0, 0, 0); stB(0, 1, 0); stA(0, 0, 0); stA(0, 1, 0);
  stB(1, 0, 64); stB(1, 1, 64);
  asm volatile("s_waitcnt vmcnt(4)" ::: "memory");
  __builtin_amdgcn_s_barrier();

  f16x8 ra[2][4], rb0[2][2], rb1[2][2];
  for (int T = 0; T < NT; T++) {
    const int buf = T & 1, kt = T * 64;
    const f16* Ah = &As[buf * 16384 + wm * 8192];
    const f16* Bh = &Bs[buf * 16384 + (wn >> 1) * 8192];
    // ---- ph0: read A(mh0)+B(nh0) [12]; stage A0(T+1); mfma q(0,0)
#pragma unroll
    for (int ks = 0; ks < 2; ks++) {
#pragma unroll
      for (int i = 0; i < 4; i++) ra[ks][i] = *(const f16x8*)&Ah[aoff[ks][i]];
#pragma unroll
      for (int j = 0; j < 2; j++) rb0[ks][j] = *(const f16x8*)&Bh[boff[ks][j]];
    }
    if (T + 1 < NT) stA(buf ^ 1, 0, kt + 64);
    __builtin_amdgcn_s_barrier();
    asm volatile("s_waitcnt lgkmcnt(0)" ::: "memory");
    __builtin_amdgcn_sched_barrier(0);
    __builtin_amdgcn_s_setprio(1);
    mfma_q<0, 0>(acc, ra, rb0);
    __builtin_amdgcn_s_setprio(0);
    __builtin_amdgcn_s_barrier();
    // ---- ph1: read B(nh1) [4]; stage A1(T+1); mfma q(0,1)
#pragma unroll
    for (int ks = 0; ks < 2; ks++)
#pragma unroll
      for (int j = 0; j < 2; j++) rb1[ks][j] = *(const f16x8*)&Bh[2048 + boff[ks][j]];
    if (T + 1 < NT) stA(buf ^ 1, 1, kt + 64);
    __builtin_amdgcn_s_barrier();
    asm volatile("s_waitcnt lgkmcnt(0)" ::: "memory");
    __builtin_amdgcn_sched_barrier(0);
    __builtin_amdgcn_s_setprio(1);
    mfma_q<0, 1>(acc, ra, rb1);
    __builtin_amdgcn_s_setprio(0);
    __builtin_amdgcn_s_barrier();
    // ---- ph2: read A(mh1) [8]; stage B0(T+2); mfma q(1,1)
#pragma unroll
    for (int ks = 0; ks < 2; ks++)
#pragma unroll
      for (int i = 0; i < 4; i++) ra[ks][i] = *(const f16x8*)&Ah[4096 + aoff[ks][i]];
    if (T + 2 < NT) stB(buf, 0, kt + 128);
    __builtin_amdgcn_s_barrier();
    asm volatile("s_waitcnt lgkmcnt(0)" ::: "memory");
    __builtin_amdgcn_sched_barrier(0);
    __builtin_amdgcn_s_setprio(1);
    mfma_q<1, 1>(acc, ra, rb1);
    __builtin_amdgcn_s_setprio(0);
    __builtin_amdgcn_s_barrier();
    // ---- ph3: stage B1(T+2); mfma q(1,0); counted vmcnt before tile barrier
    if (T + 2 < NT) stB(buf, 1, kt + 128);
    __builtin_amdgcn_s_barrier();
    __builtin_amdgcn_s_setprio(1);
    mfma_q<1, 0>(acc, ra, rb0);
    __builtin_amdgcn_s_setprio(0);
    if (T < NT - 2) asm volatile("s_waitcnt vmcnt(4)" ::: "memory");
    else            asm volatile("s_waitcnt vmcnt(0)" ::: "memory");
    __builtin_amdgcn_s_barrier();
  }

  // epilogue. C/D layout: col = lane&15, row = (lane>>4)*4 + t
  const int r0 = bm * 256 + wm * 128 + g * 4;
  const int c0 = bn * 256 + wn * 64 + l15;
#pragma unroll
  for (int mi = 0; mi < 8; mi++) {
#pragma unroll
    for (int nj = 0; nj < 4; nj++) {
      int rowb = r0 + mi * 16;
      int col = c0 + nj * 16;
      if constexpr (OP == OP_SILU) {
        f16* C = (f16*)Cp;
#pragma unroll
        for (int t = 0; t < 4; t++) {
          float v = acc[mi][nj][t];
          C[(long)(rowb + t) * ldc + col] = (f16)(v / (1.f + __expf(-v)));
        }
      } else if constexpr (OP == OP_UPG) {
        f16* C = (f16*)Cp;
#pragma unroll
        for (int t = 0; t < 4; t++) {
          long idx = (long)(rowb + t) * ldc + col;
          C[idx] = (f16)((float)G[idx] * acc[mi][nj][t]);
        }
      } else if constexpr (OP == OP_QKV) {
        f16* C = (f16*)Cp;
        if (bn < 16) {  // q or k rows
          f16* Cq = C + (bn >= 8 ? (long)M_ * D_ : 0);
          int cc = col & 2047;
#pragma unroll
          for (int t = 0; t < 4; t++) Cq[(long)(rowb + t) * D_ + cc] = (f16)acc[mi][nj][t];
        } else {        // v: write transposed vT[(b*H+h)*HD+hd][s]
          f16* Cv = C + (long)2 * M_ * D_;
          int colv = col - 4096;
          int b = rowb >> 9, s0 = rowb & 511, h = colv >> 6, hd = colv & 63;
          f16x4 pk;
#pragma unroll
          for (int t = 0; t < 4; t++) pk[t] = (f16)acc[mi][nj][t];
          *(f16x4*)&Cv[((long)(b * H_ + h) * HD_ + hd) * S_ + s0] = pk;
        }
      }
    }
  }
}

// ================== proven 128-tile m97-structure GEMM =====================
template <int BM, int BN, int WR, int WC, int OP, int BK>
__global__ __launch_bounds__(256, 2) void gemm_k(
    const f16* __restrict__ A, int lda,
    const f16* __restrict__ B, int ldb,
    void* __restrict__ Cp, int ldc,
    int K, int bh0, const float* __restrict__ relmean,
    const f16* __restrict__ B2) {
  static_assert(WR * WC == 4, "4-wave blocks assumed");
  static_assert(BK == 32 || BK == 64, "");
  constexpr bool GU = (OP == OP_GU);
  constexpr int WM = BM / WR, WN = BN / WC;
  constexpr int IM = WM / 16, IN = WN / 16;
  constexpr int RR = (BK == 64) ? 8 : 16;
  constexpr int CA = BM * BK / 2048;
  constexpr int CB = BN * BK / 2048;
  constexpr int KS = BK / 32;
  __shared__ __align__(16) f16 As[BM * BK];
  __shared__ __align__(16) f16 Bs[(GU ? 2 : 1) * BN * BK];
  const int tid = threadIdx.x, wave = tid >> 6, lane = tid & 63;
  const int wm = wave / WC, wn = wave % WC;
  const int bn = blockIdx.x, bm = blockIdx.y, bz = blockIdx.z;

  long aoff = 0, boff = 0;
  if constexpr (OP == OP_QKT) {
    int bh = bh0 + bz;
    long hb = (long)(bh >> 5) * (S_ * D_) + (long)(bh & (H_ - 1)) * HD_;
    aoff = hb; boff = hb;
  }
  if constexpr (OP == OP_PV) {
    int bh = bh0 + bz;
    aoff = (long)bz * S_ * S_;
    boff = (long)bh * HD_ * S_;
  }
  if constexpr (OP == OP_QKV) boff = (long)bz * D_ * D_;

  const f16* Ab = A + aoff + (long)bm * BM * lda;
  const f16* Bb = B + boff + (long)bn * BN * ldb;
  const f16* Bb2 = nullptr;
  if constexpr (GU) Bb2 = B2 + (long)bn * BN * ldb;

  f32x4 acc[IM][IN], acc2[GU ? IM : 1][GU ? IN : 1];
#pragma unroll
  for (int i = 0; i < IM; i++)
#pragma unroll
    for (int j = 0; j < IN; j++) {
      acc[i][j] = {0.f, 0.f, 0.f, 0.f};
      if constexpr (GU) acc2[i][j] = {0.f, 0.f, 0.f, 0.f};
    }

  const int lrr = (BK == 64) ? (lane >> 3) : (lane >> 2);
  const int lcc = (BK == 64) ? (lane & 7) : (lane & 3);
  const int scc = (BK == 64) ? (lcc ^ (lrr & 7)) : lcc;
  const int g = lane >> 4, l15 = lane & 15;

  for (int kt = 0; kt < K; kt += BK) {
    if (kt) __syncthreads();
#pragma unroll
    for (int c = 0; c < CA; c++) {
      int reg = wave * CA + c;
      gl_lds16(Ab + (long)(reg * RR + lrr) * lda + kt + scc * 8, &As[reg * 512]);
    }
#pragma unroll
    for (int c = 0; c < CB; c++) {
      int reg = wave * CB + c;
      gl_lds16(Bb + (long)(reg * RR + lrr) * ldb + kt + scc * 8, &Bs[reg * 512]);
      if constexpr (GU)
        gl_lds16(Bb2 + (long)(reg * RR + lrr) * ldb + kt + scc * 8,
                 &Bs[BN * BK + reg * 512]);
    }
    __syncthreads();
    f16x8 af[KS][IM], bf[KS][IN], bf2[GU ? KS : 1][GU ? IN : 1];
#pragma unroll
    for (int s = 0; s < KS; s++) {
#pragma unroll
      for (int i = 0; i < IM; i++) {
        int row = wm * WM + i * 16 + l15;
        int cidx = s * 4 + g;
        if constexpr (BK == 64) cidx ^= (row & 7);
        af[s][i] = *(const f16x8*)&As[row * BK + cidx * 8];
      }
#pragma unroll
      for (int j = 0; j < IN; j++) {
        int colL = wn * WN + j * 16 + l15;
        int cidx = s * 4 + g;
        if constexpr (BK == 64) cidx ^= (colL & 7);
        bf[s][j] = *(const f16x8*)&Bs[colL * BK + cidx * 8];
        if constexpr (GU) bf2[s][j] = *(const f16x8*)&Bs[BN * BK + colL * BK + cidx * 8];
      }
    }
#pragma unroll
    for (int s = 0; s < KS; s++)
#pragma unroll
      for (int i = 0; i < IM; i++)
#pragma unroll
        for (int j = 0; j < IN; j++) {
          acc[i][j] = __builtin_amdgcn_mfma_f32_16x16x32_f16(af[s][i], bf[s][j], acc[i][j], 0, 0, 0);
          if constexpr (GU)
            acc2[i][j] = __builtin_amdgcn_mfma_f32_16x16x32_f16(af[s][i], bf2[s][j], acc2[i][j], 0, 0, 0);
        }
  }

  const int r0 = bm * BM + wm * WM + (lane >> 4) * 4;
  const int c0 = bn * BN + wn * WN + l15;
#pragma unroll
  for (int i = 0; i < IM; i++) {
#pragma unroll
    for (int j = 0; j < IN; j++) {
      int rowb = r0 + i * 16;
      int col = c0 + j * 16;
      if constexpr (OP == OP_F32) {
        float* C = (float*)Cp;
#pragma unroll
        for (int t = 0; t < 4; t++) C[(long)(rowb + t) * ldc + col] = acc[i][j][t];
      } else if constexpr (OP == OP_ADD) {
        float* C = (float*)Cp;
#pragma unroll
        for (int t = 0; t < 4; t++) C[(long)(rowb + t) * ldc + col] += acc[i][j][t];
      } else if constexpr (OP == OP_GU) {
        f16* C = (f16*)Cp;
#pragma unroll
        for (int t = 0; t < 4; t++) {
          float gg = acc[i][j][t], u = acc2[i][j][t];
          C[(long)(rowb + t) * ldc + col] = (f16)(gg / (1.f + __expf(-gg)) * u);
        }
      } else if constexpr (OP == OP_QKT) {
        f16* C = (f16*)Cp + (long)bz * S_ * S_;
#pragma unroll
        for (int t = 0; t < 4; t++) {
          int r = rowb + t;
          C[(long)r * S_ + col] = (f16)(acc[i][j][t] * 0.125f + relmean[col - r + 511]);
        }
      } else if constexpr (OP == OP_PV) {
        int bh = bh0 + bz;
        f16* C = (f16*)Cp + (long)(bh >> 5) * (S_ * D_) + (long)(bh & (H_ - 1)) * HD_;
#pragma unroll
        for (int t = 0; t < 4; t++) C[(long)(rowb + t) * ldc + col] = (f16)acc[i][j][t];
      } else if constexpr (OP == OP_QKV) {
        f16* C = (f16*)Cp;
        if (bz < 2) {
          f16* Cq = C + (long)bz * M_ * D_;
#pragma unroll
          for (int t = 0; t < 4; t++) Cq[(long)(rowb + t) * ldc + col] = (f16)acc[i][j][t];
        } else {
          f16* Cv = C + (long)2 * M_ * D_;
          int b = rowb >> 9, s0 = rowb & 511, h = col >> 6, hd = col & 63;
          f16x4 pk;
#pragma unroll
          for (int t = 0; t < 4; t++) pk[t] = (f16)acc[i][j][t];
          *(f16x4*)&Cv[((long)(b * H_ + h) * HD_ + hd) * S_ + s0] = pk;
        }
      }
    }
  }
}

// Fused attention: per block = one (bh, 128-row q-tile). 8 waves, 512 threads.
__global__ __launch_bounds__(512, 2) void fattn_k(
    const f16* __restrict__ Q, const f16* __restrict__ Kg,
    const f16* __restrict__ Vt, f16* __restrict__ Ctx,
    const float* __restrict__ rel) {
  __shared__ __align__(16) f16 Ks[512 * 64];
  __shared__ __align__(16) f16 Vs[64 * 512];
  __shared__ float rms[1024];
  const int tid = threadIdx.x, wave = tid >> 6, lane = tid & 63;
  const int g = lane >> 4, l15 = lane & 15;
  const int lrr = lane >> 3, lcc = lane & 7;
  const int bm = blockIdx.x, bh = blockIdx.y;
  const int b = bh >> 5, h = bh & 31;
  const long qrow0 = (long)b * S_ + bm * 128;
  const long krow0 = (long)b * S_;
  const int hoff = h * HD_;

#pragma unroll
  for (int c = 0; c < 8; c++) {
    int reg = wave * 8 + c;
    gl_lds16(Kg + (krow0 + reg * 8 + lrr) * D_ + hoff + (lcc ^ lrr) * 8,
             &Ks[reg * 512]);
  }
  const f16* vb = Vt + (long)bh * HD_ * S_;
#pragma unroll
  for (int c = 0; c < 8; c++) {
    int reg = wave * 8 + c;
    int rb = reg >> 3, cb = reg & 7;
    gl_lds16(vb + (long)(rb * 8 + lrr) * S_ + cb * 64 + (lcc ^ lrr) * 8,
             &Vs[reg * 512]);
  }
  for (int i = tid; i < 1023; i += 512) rms[i] = rel[i];

  f16x8 aq[2];
#pragma unroll
  for (int ks = 0; ks < 2; ks++)
    aq[ks] = *(const f16x8*)&Q[(qrow0 + wave * 16 + l15) * D_ + hoff + ks * 32 + g * 8];

  __syncthreads();

  f32x4 acc[32];
#pragma unroll
  for (int jn = 0; jn < 32; jn++) acc[jn] = {0.f, 0.f, 0.f, 0.f};
#pragma unroll
  for (int jn = 0; jn < 32; jn++) {
    int r = jn * 16 + l15;
    f16x8 b0 = *(const f16x8*)&Ks[r * 64 + ((g) ^ (r & 7)) * 8];
    f16x8 b1 = *(const f16x8*)&Ks[r * 64 + ((4 + g) ^ (r & 7)) * 8];
    acc[jn] = __builtin_amdgcn_mfma_f32_16x16x32_f16(aq[0], b0, acc[jn], 0, 0, 0);
    acc[jn] = __builtin_amdgcn_mfma_f32_16x16x32_f16(aq[1], b1, acc[jn], 0, 0, 0);
  }

  const int qr0 = bm * 128 + wave * 16 + g * 4;
  float mx[4] = {-1e30f, -1e30f, -1e30f, -1e30f}, sum[4] = {0.f, 0.f, 0.f, 0.f};
#pragma unroll
  for (int t = 0; t < 4; t++) {
    int bb = l15 - (qr0 + t) + 511;
#pragma unroll
    for (int jn = 0; jn < 32; jn++) {
      float v = acc[jn][t] * 0.125f + rms[bb + jn * 16];
      acc[jn][t] = v;
      mx[t] = fmaxf(mx[t], v);
    }
  }
#pragma unroll
  for (int off = 8; off; off >>= 1)
#pragma unroll
    for (int t = 0; t < 4; t++) mx[t] = fmaxf(mx[t], __shfl_xor(mx[t], off));
#pragma unroll
  for (int t = 0; t < 4; t++)
#pragma unroll
    for (int jn = 0; jn < 32; jn++) {
      float e = __expf(acc[jn][t] - mx[t]);
      acc[jn][t] = e;
      sum[t] += e;
    }
#pragma unroll
  for (int off = 8; off; off >>= 1)
#pragma unroll
    for (int t = 0; t < 4; t++) sum[t] += __shfl_xor(sum[t], off);
  float rs[4];
#pragma unroll
  for (int t = 0; t < 4; t++) rs[t] = 1.f / sum[t];

  __syncthreads();

  f16* Pb = &Ks[wave * 4096];
  f32x4 aco[4];
#pragma unroll
  for (int jv = 0; jv < 4; jv++) aco[jv] = {0.f, 0.f, 0.f, 0.f};
#pragma unroll
  for (int hh = 0; hh < 2; hh++) {
#pragma unroll
    for (int jl = 0; jl < 16; jl++) {
      int jn = hh * 16 + jl;
      f16x4 w;
#pragma unroll
      for (int t = 0; t < 4; t++) w[t] = (f16)(acc[jn][t] * rs[t]);
      *(f16x4*)&Pb[(jl * 16 + l15) * 16 + g * 4] = w;
    }
#pragma unroll
    for (int kl = 0; kl < 8; kl++) {
      f16x8 ap;
#pragma unroll
      for (int i = 0; i < 8; i++)
        ap[i] = Pb[(kl * 32 + g * 8 + i) * 16 + l15];
#pragma unroll
      for (int jv = 0; jv < 4; jv++) {
        int r = jv * 16 + l15, c = (hh * 8 + kl) * 4 + g;
        f16x8 bv = *(const f16x8*)&Vs[(r >> 3) * 4096 + (c >> 3) * 512 +
                                      (r & 7) * 64 + ((c & 7) ^ (r & 7)) * 8];
        aco[jv] = __builtin_amdgcn_mfma_f32_16x16x32_f16(ap, bv, aco[jv], 0, 0, 0);
      }
    }
  }

#pragma unroll
  for (int jv = 0; jv < 4; jv++)
#pragma unroll
    for (int t = 0; t < 4; t++)
      Ctx[(qrow0 + wave * 16 + g * 4 + t) * D_ + hoff + jv * 16 + l15] =
          (f16)aco[jv][t];
}

// fp32 [K][N] slice -> f16 [N][K] (NT weight). 64x64 tiles via LDS.
__global__ __launch_bounds__(256) void transpose_k(
    const float* __restrict__ in, int ldin, int k0, int n0,
    f16* __restrict__ out, int ldout) {
  __shared__ f16 t[64][68];
  const int kb = blockIdx.x * 64, nb = blockIdx.y * 64;
  const int tid = threadIdx.x;
  {
    const int kr = tid >> 4, nc = (tid & 15) * 4;
    const float* src = in + (long)(k0 + kb) * ldin + (n0 + nb);
#pragma unroll
    for (int i = 0; i < 4; i++) {
      int k = kr + i * 16;
      f32x4 v = *(const f32x4*)&src[(long)k * ldin + nc];
#pragma unroll
      for (int j = 0; j < 4; j++) t[nc + j][k] = (f16)v[j];
    }
  }
  __syncthreads();
  {
    const int n = tid >> 2, kc = (tid & 3) * 16;
    f16* dst = out + (long)(nb + n) * ldout + (kb + kc);
#pragma unroll
    for (int j = 0; j < 4; j++)
      *(f16x4*)&dst[j * 4] = *(const f16x4*)&t[n][kc + j * 4];
  }
}

__global__ void cvt_f16_k(const float* __restrict__ in, f16* __restrict__ out, int n4) {
  int i = blockIdx.x * 256 + threadIdx.x;
  if (i >= n4) return;
  f32x4 v = ((const f32x4*)in)[i];
  f16x4 o;
#pragma unroll
  for (int t = 0; t < 4; t++) o[t] = (f16)v[t];
  ((f16x4*)out)[i] = o;
}

__global__ void relmean_k(const float* __restrict__ rel, float* __restrict__ rm) {
  int i = blockIdx.x * 256 + threadIdx.x;
  if (i >= 1023) return;
  float s = 0.f;
#pragma unroll 8
  for (int d = 0; d < 64; d++) s += rel[i * 64 + d];
  rm[i] = s * (1.f / 64.f);
}

// h1h = (f16) LN(X + Y) * g + b
__global__ __launch_bounds__(256) void ln1_k(const float* __restrict__ X,
                                             const float* __restrict__ Y,
                                             const float* __restrict__ g,
                                             const float* __restrict__ b,
                                             f16* __restrict__ outH) {
  int row = blockIdx.x;
  const float* x = X + (long)row * D_;
  const float* y = Y + (long)row * D_;
  int t = threadIdx.x;
  float v[8], sum = 0.f, sq = 0.f;
#pragma unroll
  for (int i = 0; i < 8; i++) {
    int idx = t + i * 256;
    float val = x[idx] + y[idx];
    v[i] = val; sum += val; sq += val * val;
  }
  for (int off = 32; off; off >>= 1) { sum += __shfl_down(sum, off); sq += __shfl_down(sq, off); }
  __shared__ float s1[4], s2[4];
  if ((t & 63) == 0) { s1[t >> 6] = sum; s2[t >> 6] = sq; }
  __syncthreads();
  sum = s1[0] + s1[1] + s1[2] + s1[3];
  sq = s2[0] + s2[1] + s2[2] + s2[3];
  float mu = sum * (1.f / D_);
  float rstd = rsqrtf(sq * (1.f / D_) - mu * mu + 1e-6f);
#pragma unroll
  for (int i = 0; i < 8; i++) {
    int idx = t + i * 256;
    outH[(long)row * D_ + idx] = (f16)((v[i] - mu) * rstd * g[idx] + b[idx]);
  }
}

// out = LN(X + Y) * g + b ; X = ffn accum (fp32), Y = h1h (f16 residual)
__global__ __launch_bounds__(256) void ln2f_k(const float* __restrict__ X,
                                              const f16* __restrict__ Y,
                                              const float* __restrict__ g,
                                              const float* __restrict__ b,
                                              float* __restrict__ outF) {
  int row = blockIdx.x;
  const float* x = X + (long)row * D_;
  const f16* y = Y + (long)row * D_;
  int t = threadIdx.x;
  float v[8], sum = 0.f, sq = 0.f;
#pragma unroll
  for (int i = 0; i < 8; i++) {
    int idx = t + i * 256;
    float val = x[idx] + (float)y[idx];
    v[i] = val; sum += val; sq += val * val;
  }
  for (int off = 32; off; off >>= 1) { sum += __shfl_down(sum, off); sq += __shfl_down(sq, off); }
  __shared__ float s1[4], s2[4];
  if ((t & 63) == 0) { s1[t >> 6] = sum; s2[t >> 6] = sq; }
  __syncthreads();
  sum = s1[0] + s1[1] + s1[2] + s1[3];
  sq = s2[0] + s2[1] + s2[2] + s2[3];
  float mu = sum * (1.f / D_);
  float rstd = rsqrtf(sq * (1.f / D_) - mu * mu + 1e-6f);
#pragma unroll
  for (int i = 0; i < 8; i++) {
    int idx = t + i * 256;
    outF[(long)row * D_ + idx] = (v[i] - mu) * rstd * g[idx] + b[idx];
  }
}

extern "C" void kernel_launch(void* const* d_in, const int* in_sizes, int n_in,
                              void* d_out, int out_size, void* d_ws, size_t ws_size,
                              hipStream_t stream) {
  const float* x    = (const float*)d_in[0];
  const float* wq   = (const float*)d_in[1];
  const float* wk   = (const float*)d_in[2];
  const float* wv   = (const float*)d_in[3];
  const float* wo   = (const float*)d_in[4];
  const float* rel  = (const float*)d_in[5];
  const float* ln1g = (const float*)d_in[6];
  const float* ln1b = (const float*)d_in[7];
  const float* gw   = (const float*)d_in[8];
  const float* uw   = (const float*)d_in[9];
  const float* dw   = (const float*)d_in[10];
  const float* ln2g = (const float*)d_in[11];
  const float* ln2b = (const float*)d_in[12];
  float* out = (float*)d_out;

  constexpr size_t MD2 = (size_t)M_ * D_ * 2;
  if (ws_size < 8 * MD2 + 4096) return;
  char* w = (char*)d_ws;
  f16* qb   = (f16*)(w + 0 * MD2);
  f16* vT   = (f16*)(w + 2 * MD2);
  f16* xb   = (f16*)(w + 3 * MD2);
  f16* s45  = (f16*)(w + 4 * MD2);
  f16* h1h  = (f16*)(w + 6 * MD2);
  f16* s7   = (f16*)(w + 7 * MD2);
  float* relmean = (float*)(w + 8 * MD2);
  // phase-disjoint aliases
  f16* ctxb = xb;
  float* attn_out = (float*)qb;            // s0-1 fp32 MxD
  f16* wqT  = s45;                         // s4: wqT,wkT,wvT contiguous
  f16* woT  = s7;
  f16* gwTh = qb;                          // s0
  f16* uwTh = (f16*)(w + 1 * MD2);         // s1
  f16* gch  = vT;                          // s2-3: M x IH f16
  f16* dwTh = s7;                          // s7: D x IH f16
  float* facc = (float*)s45;               // s4-5: M x D fp32 ffn accumulator

  // --- prep ---
  cvt_f16_k<<<M_ * D_ / 4 / 256, 256, 0, stream>>>(x, xb, M_ * D_ / 4);
  relmean_k<<<4, 256, 0, stream>>>(rel, relmean);
  transpose_k<<<dim3(32, 32), 256, 0, stream>>>(wq, D_, 0, 0, wqT, D_);
  transpose_k<<<dim3(32, 32), 256, 0, stream>>>(wk, D_, 0, 0, wqT + (size_t)D_ * D_, D_);
  transpose_k<<<dim3(32, 32), 256, 0, stream>>>(wv, D_, 0, 0, wqT + 2 * (size_t)D_ * D_, D_);
  transpose_k<<<dim3(32, 32), 256, 0, stream>>>(wo, D_, 0, 0, woT, D_);

  // --- QKV merged via 8-phase 256^2 (N = 6144 contiguous wqT/wkT/wvT) ---
  gemm8_k<OP_QKV><<<dim3(24, 16), 512, 0, stream>>>(
      xb, D_, wqT, D_, qb, D_, D_, nullptr);

  // --- fused attention ---
  fattn_k<<<dim3(4, 256), 512, 0, stream>>>(
      qb, qb + (size_t)M_ * D_, vT, ctxb, relmean);

  // --- output projection + LN1 ---
  gemm_k<128, 128, 2, 2, OP_F32, 32><<<dim3(16, 32, 1), 256, 0, stream>>>(
      ctxb, D_, woT, D_, attn_out, D_, D_, 0, nullptr, nullptr);
  ln1_k<<<M_, 256, 0, stream>>>(x, attn_out, ln1g, ln1b, h1h);

  // --- FFN in two I-halves: gate/up via 8-phase, down via 128-tile accum ---
  for (int h = 0; h < 2; h++) {
    transpose_k<<<dim3(32, 64), 256, 0, stream>>>(gw, I_, 0, h * IH_, gwTh, D_);
    transpose_k<<<dim3(32, 64), 256, 0, stream>>>(uw, I_, 0, h * IH_, uwTh, D_);
    transpose_k<<<dim3(64, 32), 256, 0, stream>>>(dw, D_, h * IH_, 0, dwTh, IH_);
    gemm8_k<OP_SILU><<<dim3(16, 16), 512, 0, stream>>>(
        h1h, D_, gwTh, D_, gch, IH_, D_, nullptr);
    gemm8_k<OP_UPG><<<dim3(16, 16), 512, 0, stream>>>(
        h1h, D_, uwTh, D_, gch, IH_, D_, gch);
    if (h == 0)
      gemm_k<128, 128, 2, 2, OP_F32, 32><<<dim3(16, 32, 1), 256, 0, stream>>>(
          gch, IH_, dwTh, IH_, facc, D_, IH_, 0, nullptr, nullptr);
    else
      gemm_k<128, 128, 2, 2, OP_ADD, 32><<<dim3(16, 32, 1), 256, 0, stream>>>(
          gch, IH_, dwTh, IH_, facc, D_, IH_, 0, nullptr, nullptr);
  }
  ln2f_k<<<M_, 256, 0, stream>>>(facc, h1h, ln2g, ln2b, out);
}